// Round 12
// baseline (203.522 us; speedup 1.0000x reference)
//
#include <hip/hip_runtime.h>
#include <hip/hip_bf16.h>
#include <math.h>

#define EPSF 1e-6f

constexpr int Bc = 8;
constexpr int Nc = 4096;
constexpr int Dc = 512;
constexpr int QKVC = 3 * Dc;  // 1536

typedef __attribute__((ext_vector_type(8))) short short8v;
typedef __attribute__((ext_vector_type(8))) unsigned short ushort8v;
typedef __attribute__((ext_vector_type(4))) float float4v;

__device__ __forceinline__ unsigned short f2bf(float f) {
    union { float f; unsigned int u; } v; v.f = f;
    unsigned int u = v.u;
    return (unsigned short)((u + 0x7fffu + ((u >> 16) & 1u)) >> 16);
}
__device__ __forceinline__ float bf2f(unsigned short h) {
    union { unsigned int u; float f; } v; v.u = ((unsigned int)h) << 16;
    return v.f;
}

typedef __attribute__((address_space(1))) const void gvoid_t;
typedef __attribute__((address_space(3))) void lvoid_t;
__device__ __forceinline__ void llds16(const void* g, void* l) {
    __builtin_amdgcn_global_load_lds((gvoid_t*)g, (lvoid_t*)l, 16, 0, 0);
}

// ---------------------------------------------------------------------------
// f32 -> bf16 conversion, 8 elems/thread
// ---------------------------------------------------------------------------
__global__ __launch_bounds__(256) void cvt_f32_bf16(
    const float* __restrict__ in, unsigned short* __restrict__ out, int n8)
{
    int i = blockIdx.x * 256 + threadIdx.x;
    if (i >= n8) return;
    float4 a = reinterpret_cast<const float4*>(in)[2 * i];
    float4 b = reinterpret_cast<const float4*>(in)[2 * i + 1];
    ushort8v o;
    o[0] = f2bf(a.x); o[1] = f2bf(a.y); o[2] = f2bf(a.z); o[3] = f2bf(a.w);
    o[4] = f2bf(b.x); o[5] = f2bf(b.y); o[6] = f2bf(b.z); o[7] = f2bf(b.w);
    reinterpret_cast<ushort8v*>(out)[i] = o;
}

// combined weight convert: w_qkv (1536x512) then w_proj (512x512)
__global__ __launch_bounds__(256) void cvt_weights(
    const float* __restrict__ wq, const float* __restrict__ wp,
    unsigned short* __restrict__ wqo, unsigned short* __restrict__ wpo)
{
    const int i = blockIdx.x * 256 + threadIdx.x;
    const int NQ = 1536 * 512 / 8;            // 98304
    const float* src; unsigned short* dst; int idx;
    if (i < NQ) { src = wq; dst = wqo; idx = i; }
    else        { src = wp; dst = wpo; idx = i - NQ; }
    float4 a = reinterpret_cast<const float4*>(src)[2 * idx];
    float4 b = reinterpret_cast<const float4*>(src)[2 * idx + 1];
    ushort8v o;
    o[0] = f2bf(a.x); o[1] = f2bf(a.y); o[2] = f2bf(a.z); o[3] = f2bf(a.w);
    o[4] = f2bf(b.x); o[5] = f2bf(b.y); o[6] = f2bf(b.z); o[7] = f2bf(b.w);
    reinterpret_cast<ushort8v*>(dst)[idx] = o;
}

// ---------------------------------------------------------------------------
// qkv GEMM (ring-3, best measured: 83us, conflicts=0)
// ---------------------------------------------------------------------------
__global__ __launch_bounds__(512, 2) void gemm_qkv(
    const unsigned short* __restrict__ A,    // [32768,512]
    const unsigned short* __restrict__ Bm,   // [1536,512]
    unsigned short* __restrict__ Cout)       // [32768,1536]
{
    constexpr int LDA = 512, LDB = 512, LDC = 1536;
    constexpr int NT = 8;
    __shared__ unsigned short ring[3][24576];

    const int t = threadIdx.x;
    const int orig = blockIdx.x;
    const int wg = (orig & 7) * 192 + (orig >> 3);   // nwg=1536, %8==0
    const int bm = (wg / 12) * 256;
    const int bn = (wg % 12) * 128;

    const int w = t >> 6, lane = t & 63;
    const int ln = lane & 15, g = lane >> 4;
    const int wr = (w >> 1) * 64;
    const int wc = (w & 1) * 64;
    const int l7 = ln & 7;

    const int rs = t >> 3;
    const int ci = t & 7;
    const int swz = ci ^ (rs & 7);
    const unsigned short* As0 = A + (size_t)(bm + rs) * LDA + swz * 8;
    const unsigned short* As1 = A + (size_t)(bm + 64 + rs) * LDA + swz * 8;
    const unsigned short* As2 = A + (size_t)(bm + 128 + rs) * LDA + swz * 8;
    const unsigned short* As3 = A + (size_t)(bm + 192 + rs) * LDA + swz * 8;
    const unsigned short* Bs0 = Bm + (size_t)(bn + rs) * LDB + swz * 8;
    const unsigned short* Bs1 = Bm + (size_t)(bn + 64 + rs) * LDB + swz * 8;

#define STAGEQ(Tt) do {                                                        \
        const int k0_ = (Tt) * 64;                                             \
        unsigned short* dA_ = &ring[(Tt) % 3][0];                              \
        unsigned short* dB_ = &ring[(Tt) % 3][16384];                          \
        llds16(As0 + k0_, dA_ + (size_t)t * 8);                                \
        llds16(As1 + k0_, dA_ + (size_t)(512 + t) * 8);                        \
        llds16(As2 + k0_, dA_ + (size_t)(1024 + t) * 8);                       \
        llds16(As3 + k0_, dA_ + (size_t)(1536 + t) * 8);                       \
        llds16(Bs0 + k0_, dB_ + (size_t)t * 8);                                \
        llds16(Bs1 + k0_, dB_ + (size_t)(512 + t) * 8);                        \
    } while (0)

    float4v acc[4][4];
#pragma unroll
    for (int i = 0; i < 4; ++i)
#pragma unroll
        for (int j = 0; j < 4; ++j) acc[i][j] = {0.f, 0.f, 0.f, 0.f};

    STAGEQ(0);
    STAGEQ(1);
    asm volatile("s_waitcnt vmcnt(6)" ::: "memory");
    __builtin_amdgcn_s_barrier();
    __builtin_amdgcn_sched_barrier(0);

#pragma unroll
    for (int T = 0; T < NT; ++T) {
        if (T + 2 < NT) STAGEQ(T + 2);

        const unsigned short* base = &ring[T % 3][0];
        short8v a[4][2], b[4][2];
#pragma unroll
        for (int i = 0; i < 4; ++i)
#pragma unroll
            for (int kk = 0; kk < 2; ++kk) {
                const int row = wr + i * 16 + ln;
                a[i][kk] = *reinterpret_cast<const short8v*>(
                    base + row * 64 + (((kk * 4 + g) ^ l7) << 3));
            }
#pragma unroll
        for (int j = 0; j < 4; ++j)
#pragma unroll
            for (int kk = 0; kk < 2; ++kk) {
                const int row = wc + j * 16 + ln;
                b[j][kk] = *reinterpret_cast<const short8v*>(
                    base + 16384 + row * 64 + (((kk * 4 + g) ^ l7) << 3));
            }

        __builtin_amdgcn_s_setprio(1);
#pragma unroll
        for (int kk = 0; kk < 2; ++kk)
#pragma unroll
            for (int i = 0; i < 4; ++i)
#pragma unroll
                for (int j = 0; j < 4; ++j)
                    acc[i][j] = __builtin_amdgcn_mfma_f32_16x16x32_bf16(
                        a[i][kk], b[j][kk], acc[i][j], 0, 0, 0);
        __builtin_amdgcn_s_setprio(0);

        if (T + 1 < NT) {
            if (T + 2 < NT)
                asm volatile("s_waitcnt vmcnt(6)" ::: "memory");
            else
                asm volatile("s_waitcnt vmcnt(0)" ::: "memory");
            __builtin_amdgcn_s_barrier();
            __builtin_amdgcn_sched_barrier(0);
        }
    }
#undef STAGEQ

#pragma unroll
    for (int i = 0; i < 4; ++i) {
        const int Rb = bm + wr + i * 16 + g * 4;
#pragma unroll
        for (int j = 0; j < 4; ++j) {
            const int Cc = bn + wc + j * 16 + ln;
            const bool do_elu = (Cc < 1024);
#pragma unroll
            for (int r = 0; r < 4; ++r) {
                float v = acc[i][j][r];
                if (do_elu) v = (v > 0.f) ? (v + 1.0f + EPSF) : (expf(v) + EPSF);
                Cout[(size_t)(Rb + r) * LDC + Cc] = f2bf(v);
            }
        }
    }
}

// ---------------------------------------------------------------------------
// kv partials v1 structure, 16 chunks (256 rows each) for 4 blocks/CU
// ---------------------------------------------------------------------------
__global__ __launch_bounds__(256) void kv_part(
    const unsigned short* __restrict__ qkv,
    float* __restrict__ kvp, float* __restrict__ ksp)
{
    const int bh = blockIdx.x, chunk = blockIdx.y;   // chunk 0..15
    const int b = bh >> 3, h = bh & 7;

    __shared__ float kt[64][68];
    __shared__ float vt[64][68];
    __shared__ float ksl[4][64];

    const int t  = threadIdx.x;
    const int e  = t & 63, dg = t >> 6;
    const int rr = t >> 3, slot = t & 7;

    float acc[16] = {};
    float ks = 0.f;

    const size_t base = ((size_t)b * Nc + (size_t)chunk * 256) * QKVC + h * 64;

    for (int n0 = 0; n0 < 256; n0 += 64) {
#pragma unroll
        for (int half = 0; half < 2; ++half) {
            const int row = rr + half * 32;
            const unsigned short* kr = qkv + base + (size_t)(n0 + row) * QKVC + Dc + slot * 8;
            const unsigned short* vr = kr + Dc;
            ushort8v kq = *reinterpret_cast<const ushort8v*>(kr);
            ushort8v vq = *reinterpret_cast<const ushort8v*>(vr);
            float4 k0 = make_float4(bf2f(kq[0]), bf2f(kq[1]), bf2f(kq[2]), bf2f(kq[3]));
            float4 k1 = make_float4(bf2f(kq[4]), bf2f(kq[5]), bf2f(kq[6]), bf2f(kq[7]));
            float4 v0 = make_float4(bf2f(vq[0]), bf2f(vq[1]), bf2f(vq[2]), bf2f(vq[3]));
            float4 v1 = make_float4(bf2f(vq[4]), bf2f(vq[5]), bf2f(vq[6]), bf2f(vq[7]));
            *reinterpret_cast<float4*>(&kt[row][slot * 8])     = k0;
            *reinterpret_cast<float4*>(&kt[row][slot * 8 + 4]) = k1;
            *reinterpret_cast<float4*>(&vt[row][slot * 8])     = v0;
            *reinterpret_cast<float4*>(&vt[row][slot * 8 + 4]) = v1;
        }
        __syncthreads();
#pragma unroll 2
        for (int nn = 0; nn < 64; ++nn) {
            const float vv = vt[nn][e];
            const float4 q0 = *reinterpret_cast<const float4*>(&kt[nn][dg * 16]);
            const float4 q1 = *reinterpret_cast<const float4*>(&kt[nn][dg * 16 + 4]);
            const float4 q2 = *reinterpret_cast<const float4*>(&kt[nn][dg * 16 + 8]);
            const float4 q3 = *reinterpret_cast<const float4*>(&kt[nn][dg * 16 + 12]);
            acc[0]  += q0.x * vv; acc[1]  += q0.y * vv; acc[2]  += q0.z * vv; acc[3]  += q0.w * vv;
            acc[4]  += q1.x * vv; acc[5]  += q1.y * vv; acc[6]  += q1.z * vv; acc[7]  += q1.w * vv;
            acc[8]  += q2.x * vv; acc[9]  += q2.y * vv; acc[10] += q2.z * vv; acc[11] += q2.w * vv;
            acc[12] += q3.x * vv; acc[13] += q3.y * vv; acc[14] += q3.z * vv; acc[15] += q3.w * vv;
        }
#pragma unroll
        for (int nn = 0; nn < 16; ++nn) ks += kt[dg * 16 + nn][e];
        __syncthreads();
    }

    float* kvpp = kvp + ((size_t)bh * 16 + chunk) * 4096;
#pragma unroll
    for (int i = 0; i < 16; ++i) kvpp[(dg * 16 + i) * 64 + e] = acc[i];

    ksl[dg][e] = ks;
    __syncthreads();
    if (t < 64) ksp[((size_t)bh * 16 + chunk) * 64 + t] =
        ksl[0][t] + ksl[1][t] + ksl[2][t] + ksl[3][t];
}

// ---------------------------------------------------------------------------
// reduce 16 chunk-partials -> kvb (bf16, [d][e] row-major) + ksum (f32)
// ---------------------------------------------------------------------------
__global__ __launch_bounds__(256) void kv_reduce(
    const float* __restrict__ kvp, const float* __restrict__ ksp,
    unsigned short* __restrict__ kvb, float* __restrict__ ksum)
{
    const int bh = blockIdx.x, t = threadIdx.x;
    const float* src = kvp + (size_t)bh * 16 * 4096;
#pragma unroll
    for (int i = 0; i < 16; ++i) {
        const int idx = i * 256 + t;
        float s = 0.f;
#pragma unroll
        for (int c = 0; c < 16; ++c) s += src[c * 4096 + idx];
        kvb[(size_t)bh * 4096 + idx] = f2bf(s);
    }
    if (t < 64) {
        float s = 0.f;
#pragma unroll
        for (int c = 0; c < 16; ++c) s += ksp[((size_t)bh * 16 + c) * 64 + t];
        ksum[bh * 64 + t] = s;
    }
}

// ---------------------------------------------------------------------------
// MT[b][c][h*64+d] = sum_e kv[b,h,d,e] * wp[c, h*64+e]   (bf16 out)
// ---------------------------------------------------------------------------
__global__ __launch_bounds__(256) void gemm_M(
    const unsigned short* __restrict__ kvb,   // [64][4096]
    const unsigned short* __restrict__ wp,    // [512][512]
    unsigned short* __restrict__ MT)          // [8][512][512]
{
    const int bh = blockIdx.x, b = bh >> 3, h = bh & 7;
    const int t = threadIdx.x, w = t >> 6, lane = t & 63;
    const int ln = lane & 15, g = lane >> 4;

    float4v acc[8][4];
#pragma unroll
    for (int i = 0; i < 8; ++i)
#pragma unroll
        for (int j = 0; j < 4; ++j) acc[i][j] = {0.f, 0.f, 0.f, 0.f};

#pragma unroll
    for (int kk = 0; kk < 2; ++kk) {
        short8v a[8], bf[4];
#pragma unroll
        for (int i = 0; i < 8; ++i)
            a[i] = *reinterpret_cast<const short8v*>(
                wp + (size_t)(w * 128 + i * 16 + ln) * 512 + h * 64 + kk * 32 + g * 8);
#pragma unroll
        for (int j = 0; j < 4; ++j)
            bf[j] = *reinterpret_cast<const short8v*>(
                kvb + (size_t)bh * 4096 + (j * 16 + ln) * 64 + kk * 32 + g * 8);
#pragma unroll
        for (int i = 0; i < 8; ++i)
#pragma unroll
            for (int j = 0; j < 4; ++j)
                acc[i][j] = __builtin_amdgcn_mfma_f32_16x16x32_bf16(a[i], bf[j], acc[i][j], 0, 0, 0);
    }

#pragma unroll
    for (int i = 0; i < 8; ++i) {
        const int c0 = w * 128 + i * 16 + g * 4;
#pragma unroll
        for (int j = 0; j < 4; ++j) {
            const int d = j * 16 + ln;
#pragma unroll
            for (int r = 0; r < 4; ++r)
                MT[(size_t)b * 262144 + (size_t)(c0 + r) * 512 + h * 64 + d] =
                    f2bf(acc[i][j][r]);
        }
    }
}

// ---------------------------------------------------------------------------
// q' = q / (q . ksum_h + eps), in place (bf16)
// ---------------------------------------------------------------------------
__global__ __launch_bounds__(256) void q_scale(
    unsigned short* __restrict__ qkv, const float* __restrict__ ksum)
{
    __shared__ float kss[512];
    const int blk = blockIdx.x;          // 1024
    const int b = blk >> 7;
    const int t = threadIdx.x;
    kss[t] = ksum[b * 512 + t];
    kss[t + 256] = ksum[b * 512 + 256 + t];
    __syncthreads();

    const int row = blk * 32 + (t >> 3);
    const int h = t & 7;
    unsigned short* p = qkv + (size_t)row * QKVC + h * 64;

    ushort8v v[8];
#pragma unroll
    for (int s = 0; s < 8; ++s) v[s] = *reinterpret_cast<const ushort8v*>(p + s * 8);

    float den = EPSF;
#pragma unroll
    for (int s = 0; s < 8; ++s)
#pragma unroll
        for (int m = 0; m < 8; ++m)
            den += bf2f(v[s][m]) * kss[h * 64 + s * 8 + m];
    const float inv = 1.0f / den;

#pragma unroll
    for (int s = 0; s < 8; ++s) {
        ushort8v o;
#pragma unroll
        for (int m = 0; m < 8; ++m) o[m] = f2bf(bf2f(v[s][m]) * inv);
        *reinterpret_cast<ushort8v*>(p + s * 8) = o;
    }
}

// ---------------------------------------------------------------------------
// out = q' @ MT_b^T + bias  (f32 out), ring-3
// ---------------------------------------------------------------------------
__global__ __launch_bounds__(512, 2) void gemm_out(
    const unsigned short* __restrict__ A,    // qkvb, lda 1536
    const unsigned short* __restrict__ Bt,   // MT [8][512][512]
    const float* __restrict__ bias,
    float* __restrict__ out)                 // [32768,512]
{
    constexpr int LDA = 1536, LDB = 512, NT = 8;
    __shared__ unsigned short ring[3][24576];

    const int t = threadIdx.x;
    const int orig = blockIdx.x;
    const int wg = (orig & 7) * 64 + (orig >> 3);   // nwg=512, %8==0
    const int bm = (wg >> 2) * 256;
    const int bn = (wg & 3) * 128;
    const unsigned short* Bm = Bt + (size_t)(bm >> 12) * 262144;

    const int w = t >> 6, lane = t & 63;
    const int ln = lane & 15, g = lane >> 4;
    const int wr = (w >> 1) * 64;
    const int wc = (w & 1) * 64;
    const int l7 = ln & 7;

    const int rs = t >> 3;
    const int ci = t & 7;
    const int swz = ci ^ (rs & 7);
    const unsigned short* As0 = A + (size_t)(bm + rs) * LDA + swz * 8;
    const unsigned short* As1 = A + (size_t)(bm + 64 + rs) * LDA + swz * 8;
    const unsigned short* As2 = A + (size_t)(bm + 128 + rs) * LDA + swz * 8;
    const unsigned short* As3 = A + (size_t)(bm + 192 + rs) * LDA + swz * 8;
    const unsigned short* Bs0 = Bm + (size_t)(bn + rs) * LDB + swz * 8;
    const unsigned short* Bs1 = Bm + (size_t)(bn + 64 + rs) * LDB + swz * 8;

#define STAGEO(Tt) do {                                                        \
        const int k0_ = (Tt) * 64;                                             \
        unsigned short* dA_ = &ring[(Tt) % 3][0];                              \
        unsigned short* dB_ = &ring[(Tt) % 3][16384];                          \
        llds16(As0 + k0_, dA_ + (size_t)t * 8);                                \
        llds16(As1 + k0_, dA_ + (size_t)(512 + t) * 8);                        \
        llds16(As2 + k0_, dA_ + (size_t)(1024 + t) * 8);                       \
        llds16(As3 + k0_, dA_ + (size_t)(1536 + t) * 8);                       \
        llds16(Bs0 + k0_, dB_ + (size_t)t * 8);                                \
        llds16(Bs1 + k0_, dB_ + (size_t)(512 + t) * 8);                        \
    } while (0)

    float4v acc[4][4];
#pragma unroll
    for (int i = 0; i < 4; ++i)
#pragma unroll
        for (int j = 0; j < 4; ++j) acc[i][j] = {0.f, 0.f, 0.f, 0.f};

    STAGEO(0);
    STAGEO(1);
    asm volatile("s_waitcnt vmcnt(6)" ::: "memory");
    __builtin_amdgcn_s_barrier();
    __builtin_amdgcn_sched_barrier(0);

#pragma unroll
    for (int T = 0; T < NT; ++T) {
        if (T + 2 < NT) STAGEO(T + 2);

        const unsigned short* base = &ring[T % 3][0];
        short8v a[4][2], b[4][2];
#pragma unroll
        for (int i = 0; i < 4; ++i)
#pragma unroll
            for (int kk = 0; kk < 2; ++kk) {
                const int row = wr + i * 16 + ln;
                a[i][kk] = *reinterpret_cast<const short8v*>(
                    base + row * 64 + (((kk * 4 + g) ^ l7) << 3));
            }
#pragma unroll
        for (int j = 0; j < 4; ++j)
#pragma unroll
            for (int kk = 0; kk < 2; ++kk) {
                const int row = wc + j * 16 + ln;
                b[j][kk] = *reinterpret_cast<const short8v*>(
                    base + 16384 + row * 64 + (((kk * 4 + g) ^ l7) << 3));
            }

        __builtin_amdgcn_s_setprio(1);
#pragma unroll
        for (int kk = 0; kk < 2; ++kk)
#pragma unroll
            for (int i = 0; i < 4; ++i)
#pragma unroll
                for (int j = 0; j < 4; ++j)
                    acc[i][j] = __builtin_amdgcn_mfma_f32_16x16x32_bf16(
                        a[i][kk], b[j][kk], acc[i][j], 0, 0, 0);
        __builtin_amdgcn_s_setprio(0);

        if (T + 1 < NT) {
            if (T + 2 < NT)
                asm volatile("s_waitcnt vmcnt(6)" ::: "memory");
            else
                asm volatile("s_waitcnt vmcnt(0)" ::: "memory");
            __builtin_amdgcn_s_barrier();
            __builtin_amdgcn_sched_barrier(0);
        }
    }
#undef STAGEO

#pragma unroll
    for (int i = 0; i < 4; ++i) {
        const int Rb = bm + wr + i * 16 + g * 4;
#pragma unroll
        for (int j = 0; j < 4; ++j) {
            const int Cc = bn + wc + j * 16 + ln;
            const float bv = bias[Cc];
#pragma unroll
            for (int r = 0; r < 4; ++r)
                out[(size_t)(Rb + r) * 512 + Cc] = acc[i][j][r] + bv;
        }
    }
}

// ---------------------------------------------------------------------------
extern "C" void kernel_launch(void* const* d_in, const int* in_sizes, int n_in,
                              void* d_out, int out_size, void* d_ws, size_t ws_size,
                              hipStream_t stream)
{
    const float* x      = (const float*)d_in[0];  // [8,4096,512]
    const float* w_qkv  = (const float*)d_in[1];  // [1536,512]
    const float* w_proj = (const float*)d_in[2];  // [512,512]
    const float* b_proj = (const float*)d_in[3];  // [512]
    float* out = (float*)d_out;

    char* ws = (char*)d_ws;
    unsigned short* qkvb = (unsigned short*)ws;                    // 96 MiB
    size_t off = (size_t)32768 * 1536 * 2;
    unsigned short* xb   = (unsigned short*)(ws + off); off += (size_t)32768 * 512 * 2;
    unsigned short* wqb  = (unsigned short*)(ws + off); off += (size_t)1536 * 512 * 2;
    unsigned short* wpb  = (unsigned short*)(ws + off); off += (size_t)512 * 512 * 2;
    float* kvp           = (float*)(ws + off);          off += (size_t)64 * 16 * 4096 * 4;
    float* ksp           = (float*)(ws + off);          off += (size_t)64 * 16 * 64 * 4;
    unsigned short* kvb  = (unsigned short*)(ws + off); off += (size_t)64 * 4096 * 2;
    float* ksumb         = (float*)(ws + off);          off += (size_t)64 * 64 * 4;
    unsigned short* MT   = (unsigned short*)(ws + off); off += (size_t)8 * 512 * 512 * 2;

    // 1) convert inputs to bf16
    cvt_f32_bf16<<<dim3((32768 * 512 / 8 + 255) / 256), dim3(256), 0, stream>>>(x, xb, 32768 * 512 / 8);
    cvt_weights<<<dim3(((1536 * 512 + 512 * 512) / 8 + 255) / 256), dim3(256), 0, stream>>>(
        w_qkv, w_proj, wqb, wpb);

    // 2) qkv = elu1(x @ w_qkv^T) (elu on cols<1024), bf16 out — ring-3
    gemm_qkv<<<dim3(1536), dim3(512), 0, stream>>>(xb, wqb, qkvb);

    // 3) kv partials (16 chunks, 4 blocks/CU) + reduce
    kv_part<<<dim3(64, 16), dim3(256), 0, stream>>>(qkvb, kvp, ksp);
    kv_reduce<<<dim3(64), dim3(256), 0, stream>>>(kvp, ksp, kvb, ksumb);

    // 4) MT_b = (kv_h @ wp_h^T) stacked, per batch
    gemm_M<<<dim3(64), dim3(256), 0, stream>>>(kvb, wpb, MT);

    // 5) q' = q / (q.ksum + eps), in place
    q_scale<<<dim3(1024), dim3(256), 0, stream>>>(qkvb, ksumb);

    // 6) out = q' @ MT_b^T + bias (f32) — ring-3
    gemm_out<<<dim3(512), dim3(512), 0, stream>>>(qkvb, MT, b_proj, out);
}

// Round 13
// 197.202 us; speedup vs baseline: 1.0320x; 1.0320x over previous
//
#include <hip/hip_runtime.h>
#include <hip/hip_bf16.h>
#include <math.h>

#define EPSF 1e-6f

constexpr int Bc = 8;
constexpr int Nc = 4096;
constexpr int Dc = 512;
constexpr int QKVC = 3 * Dc;  // 1536

typedef __attribute__((ext_vector_type(8))) short short8v;
typedef __attribute__((ext_vector_type(8))) unsigned short ushort8v;
typedef __attribute__((ext_vector_type(4))) float float4v;

__device__ __forceinline__ unsigned short f2bf(float f) {
    union { float f; unsigned int u; } v; v.f = f;
    unsigned int u = v.u;
    return (unsigned short)((u + 0x7fffu + ((u >> 16) & 1u)) >> 16);
}
__device__ __forceinline__ float bf2f(unsigned short h) {
    union { unsigned int u; float f; } v; v.u = ((unsigned int)h) << 16;
    return v.f;
}
// packed f32x2 -> bf16x2, RNE (bit-identical to f2bf for normal inputs)
__device__ __forceinline__ unsigned int cvtpk(float lo, float hi) {
    unsigned int r;
    asm("v_cvt_pk_bf16_f32 %0, %1, %2" : "=v"(r) : "v"(lo), "v"(hi));
    return r;
}

typedef __attribute__((address_space(1))) const void gvoid_t;
typedef __attribute__((address_space(3))) void lvoid_t;
__device__ __forceinline__ void llds16(const void* g, void* l) {
    __builtin_amdgcn_global_load_lds((gvoid_t*)g, (lvoid_t*)l, 16, 0, 0);
}

// ---------------------------------------------------------------------------
// combined weight convert: w_qkv (1536x512) then w_proj (512x512)
// ---------------------------------------------------------------------------
__global__ __launch_bounds__(256) void cvt_weights(
    const float* __restrict__ wq, const float* __restrict__ wp,
    unsigned short* __restrict__ wqo, unsigned short* __restrict__ wpo)
{
    const int i = blockIdx.x * 256 + threadIdx.x;
    const int NQ = 1536 * 512 / 8;            // 98304
    const float* src; unsigned short* dst; int idx;
    if (i < NQ) { src = wq; dst = wqo; idx = i; }
    else        { src = wp; dst = wpo; idx = i - NQ; }
    float4 a = reinterpret_cast<const float4*>(src)[2 * idx];
    float4 b = reinterpret_cast<const float4*>(src)[2 * idx + 1];
    ushort8v o;
    o[0] = f2bf(a.x); o[1] = f2bf(a.y); o[2] = f2bf(a.z); o[3] = f2bf(a.w);
    o[4] = f2bf(b.x); o[5] = f2bf(b.y); o[6] = f2bf(b.z); o[7] = f2bf(b.w);
    reinterpret_cast<ushort8v*>(dst)[idx] = o;
}

// ---------------------------------------------------------------------------
// qkv GEMM, fused x-convert: A read as f32 + reg-staged (cvt_pk -> ds_write),
// B keeps ring-3 global_load_lds with counted vmcnt. Ring safety:
//  - A slot (T+1)%3 ds_written end of iter T; last read iter T-2 (barriered).
//  - B slot (T+2)%3 glds'd during iter T; last read iter T-1 (barriered).
// End-of-iter: vmcnt(2) keeps only B(T+2) glds in flight (issued LAST).
// ---------------------------------------------------------------------------
__global__ __launch_bounds__(512, 2) void gemm_qkv(
    const float* __restrict__ X,             // [32768,512] f32
    const unsigned short* __restrict__ Bm,   // [1536,512]  bf16
    unsigned short* __restrict__ Cout)       // [32768,1536] bf16
{
    constexpr int LDA = 512, LDB = 512, LDC = 1536;
    constexpr int NT = 8;
    __shared__ unsigned short ring[3][24576]; // A: 16384 ushort, B: 8192

    const int t = threadIdx.x;
    const int orig = blockIdx.x;
    const int wg = (orig & 7) * 192 + (orig >> 3);   // nwg=1536, %8==0
    const int bm = (wg / 12) * 256;
    const int bn = (wg % 12) * 128;

    const int w = t >> 6, lane = t & 63;
    const int ln = lane & 15, g = lane >> 4;
    const int wr = (w >> 1) * 64;
    const int wc = (w & 1) * 64;
    const int l7 = ln & 7;

    const int rs = t >> 3;
    const int ci = t & 7;
    const int swz = ci ^ (rs & 7);   // pre-swizzled source (rule 21)
    const float* Xs0 = X + (size_t)(bm + rs) * LDA + swz * 8;
    const float* Xs1 = X + (size_t)(bm + 64 + rs) * LDA + swz * 8;
    const float* Xs2 = X + (size_t)(bm + 128 + rs) * LDA + swz * 8;
    const float* Xs3 = X + (size_t)(bm + 192 + rs) * LDA + swz * 8;
    const unsigned short* Bs0 = Bm + (size_t)(bn + rs) * LDB + swz * 8;
    const unsigned short* Bs1 = Bm + (size_t)(bn + 64 + rs) * LDB + swz * 8;

    float4 Ar[4][2];

#define ISSUE_A(Tt) do {                                                       \
        const int k0_ = (Tt) * 64;                                             \
        Ar[0][0] = *reinterpret_cast<const float4*>(Xs0 + k0_);                \
        Ar[0][1] = *reinterpret_cast<const float4*>(Xs0 + k0_ + 4);            \
        Ar[1][0] = *reinterpret_cast<const float4*>(Xs1 + k0_);                \
        Ar[1][1] = *reinterpret_cast<const float4*>(Xs1 + k0_ + 4);            \
        Ar[2][0] = *reinterpret_cast<const float4*>(Xs2 + k0_);                \
        Ar[2][1] = *reinterpret_cast<const float4*>(Xs2 + k0_ + 4);            \
        Ar[3][0] = *reinterpret_cast<const float4*>(Xs3 + k0_);                \
        Ar[3][1] = *reinterpret_cast<const float4*>(Xs3 + k0_ + 4);            \
    } while (0)

#define STAGEB(Tt) do {                                                        \
        const int k0_ = (Tt) * 64;                                             \
        unsigned short* dB_ = &ring[(Tt) % 3][16384];                          \
        llds16(Bs0 + k0_, dB_ + (size_t)t * 8);                                \
        llds16(Bs1 + k0_, dB_ + (size_t)(512 + t) * 8);                        \
    } while (0)

#define WRITE_A(Tt) do {                                                       \
        unsigned short* dA_ = &ring[(Tt) % 3][0];                              \
        uint4 w0, w1, w2, w3;                                                  \
        w0.x = cvtpk(Ar[0][0].x, Ar[0][0].y); w0.y = cvtpk(Ar[0][0].z, Ar[0][0].w); \
        w0.z = cvtpk(Ar[0][1].x, Ar[0][1].y); w0.w = cvtpk(Ar[0][1].z, Ar[0][1].w); \
        w1.x = cvtpk(Ar[1][0].x, Ar[1][0].y); w1.y = cvtpk(Ar[1][0].z, Ar[1][0].w); \
        w1.z = cvtpk(Ar[1][1].x, Ar[1][1].y); w1.w = cvtpk(Ar[1][1].z, Ar[1][1].w); \
        w2.x = cvtpk(Ar[2][0].x, Ar[2][0].y); w2.y = cvtpk(Ar[2][0].z, Ar[2][0].w); \
        w2.z = cvtpk(Ar[2][1].x, Ar[2][1].y); w2.w = cvtpk(Ar[2][1].z, Ar[2][1].w); \
        w3.x = cvtpk(Ar[3][0].x, Ar[3][0].y); w3.y = cvtpk(Ar[3][0].z, Ar[3][0].w); \
        w3.z = cvtpk(Ar[3][1].x, Ar[3][1].y); w3.w = cvtpk(Ar[3][1].z, Ar[3][1].w); \
        *reinterpret_cast<uint4*>(dA_ + (size_t)t * 8)            = w0;        \
        *reinterpret_cast<uint4*>(dA_ + (size_t)(512 + t) * 8)    = w1;        \
        *reinterpret_cast<uint4*>(dA_ + (size_t)(1024 + t) * 8)   = w2;        \
        *reinterpret_cast<uint4*>(dA_ + (size_t)(1536 + t) * 8)   = w3;        \
    } while (0)

    float4v acc[4][4];
#pragma unroll
    for (int i = 0; i < 4; ++i)
#pragma unroll
        for (int j = 0; j < 4; ++j) acc[i][j] = {0.f, 0.f, 0.f, 0.f};

    // prologue: A(0) loads + B(0),B(1) glds; drain all but B(1); write A(0)
    ISSUE_A(0);
    STAGEB(0);
    STAGEB(1);
    asm volatile("s_waitcnt vmcnt(2)" ::: "memory");
    WRITE_A(0);
    asm volatile("s_waitcnt lgkmcnt(0)" ::: "memory");
    __builtin_amdgcn_s_barrier();
    __builtin_amdgcn_sched_barrier(0);

#pragma unroll
    for (int T = 0; T < NT; ++T) {
        if (T + 1 < NT) ISSUE_A(T + 1);      // f32 loads (issued first)
        if (T + 2 < NT) STAGEB(T + 2);       // glds (issued LAST -> newest)

        const unsigned short* base = &ring[T % 3][0];
        short8v a[4][2], b[4][2];
#pragma unroll
        for (int i = 0; i < 4; ++i)
#pragma unroll
            for (int kk = 0; kk < 2; ++kk) {
                const int row = wr + i * 16 + ln;
                a[i][kk] = *reinterpret_cast<const short8v*>(
                    base + row * 64 + (((kk * 4 + g) ^ l7) << 3));
            }
#pragma unroll
        for (int j = 0; j < 4; ++j)
#pragma unroll
            for (int kk = 0; kk < 2; ++kk) {
                const int row = wc + j * 16 + ln;
                b[j][kk] = *reinterpret_cast<const short8v*>(
                    base + 16384 + row * 64 + (((kk * 4 + g) ^ l7) << 3));
            }

        __builtin_amdgcn_s_setprio(1);
#pragma unroll
        for (int kk = 0; kk < 2; ++kk)
#pragma unroll
            for (int i = 0; i < 4; ++i)
#pragma unroll
                for (int j = 0; j < 4; ++j)
                    acc[i][j] = __builtin_amdgcn_mfma_f32_16x16x32_bf16(
                        a[i][kk], b[j][kk], acc[i][j], 0, 0, 0);
        __builtin_amdgcn_s_setprio(0);

        if (T + 1 < NT) {
            if (T + 2 < NT)
                asm volatile("s_waitcnt vmcnt(2)" ::: "memory");  // keep B(T+2)
            else
                asm volatile("s_waitcnt vmcnt(0)" ::: "memory");
            WRITE_A(T + 1);
            asm volatile("s_waitcnt lgkmcnt(0)" ::: "memory");
            __builtin_amdgcn_s_barrier();
            __builtin_amdgcn_sched_barrier(0);
        }
    }
#undef ISSUE_A
#undef STAGEB
#undef WRITE_A

    // epilogue: D[row=g*4+r, col=ln]; elu+1+eps on cols<1024; bf16 out
#pragma unroll
    for (int i = 0; i < 4; ++i) {
        const int Rb = bm + wr + i * 16 + g * 4;
#pragma unroll
        for (int j = 0; j < 4; ++j) {
            const int Cc = bn + wc + j * 16 + ln;
            const bool do_elu = (Cc < 1024);
#pragma unroll
            for (int r = 0; r < 4; ++r) {
                float v = acc[i][j][r];
                if (do_elu) v = (v > 0.f) ? (v + 1.0f + EPSF) : (expf(v) + EPSF);
                Cout[(size_t)(Rb + r) * LDC + Cc] = f2bf(v);
            }
        }
    }
}

// ---------------------------------------------------------------------------
// kv partials v1 (proven): per (bh, chunk of 512 rows)
// ---------------------------------------------------------------------------
__global__ __launch_bounds__(256) void kv_part(
    const unsigned short* __restrict__ qkv,
    float* __restrict__ kvp, float* __restrict__ ksp)
{
    const int bh = blockIdx.x, chunk = blockIdx.y;
    const int b = bh >> 3, h = bh & 7;

    __shared__ float kt[64][68];
    __shared__ float vt[64][68];
    __shared__ float ksl[4][64];

    const int t  = threadIdx.x;
    const int e  = t & 63, dg = t >> 6;
    const int rr = t >> 3, slot = t & 7;

    float acc[16] = {};
    float ks = 0.f;

    const size_t base = ((size_t)b * Nc + (size_t)chunk * 512) * QKVC + h * 64;

    for (int n0 = 0; n0 < 512; n0 += 64) {
#pragma unroll
        for (int half = 0; half < 2; ++half) {
            const int row = rr + half * 32;
            const unsigned short* kr = qkv + base + (size_t)(n0 + row) * QKVC + Dc + slot * 8;
            const unsigned short* vr = kr + Dc;
            ushort8v kq = *reinterpret_cast<const ushort8v*>(kr);
            ushort8v vq = *reinterpret_cast<const ushort8v*>(vr);
            float4 k0 = make_float4(bf2f(kq[0]), bf2f(kq[1]), bf2f(kq[2]), bf2f(kq[3]));
            float4 k1 = make_float4(bf2f(kq[4]), bf2f(kq[5]), bf2f(kq[6]), bf2f(kq[7]));
            float4 v0 = make_float4(bf2f(vq[0]), bf2f(vq[1]), bf2f(vq[2]), bf2f(vq[3]));
            float4 v1 = make_float4(bf2f(vq[4]), bf2f(vq[5]), bf2f(vq[6]), bf2f(vq[7]));
            *reinterpret_cast<float4*>(&kt[row][slot * 8])     = k0;
            *reinterpret_cast<float4*>(&kt[row][slot * 8 + 4]) = k1;
            *reinterpret_cast<float4*>(&vt[row][slot * 8])     = v0;
            *reinterpret_cast<float4*>(&vt[row][slot * 8 + 4]) = v1;
        }
        __syncthreads();
#pragma unroll 2
        for (int nn = 0; nn < 64; ++nn) {
            const float vv = vt[nn][e];
            const float4 q0 = *reinterpret_cast<const float4*>(&kt[nn][dg * 16]);
            const float4 q1 = *reinterpret_cast<const float4*>(&kt[nn][dg * 16 + 4]);
            const float4 q2 = *reinterpret_cast<const float4*>(&kt[nn][dg * 16 + 8]);
            const float4 q3 = *reinterpret_cast<const float4*>(&kt[nn][dg * 16 + 12]);
            acc[0]  += q0.x * vv; acc[1]  += q0.y * vv; acc[2]  += q0.z * vv; acc[3]  += q0.w * vv;
            acc[4]  += q1.x * vv; acc[5]  += q1.y * vv; acc[6]  += q1.z * vv; acc[7]  += q1.w * vv;
            acc[8]  += q2.x * vv; acc[9]  += q2.y * vv; acc[10] += q2.z * vv; acc[11] += q2.w * vv;
            acc[12] += q3.x * vv; acc[13] += q3.y * vv; acc[14] += q3.z * vv; acc[15] += q3.w * vv;
        }
#pragma unroll
        for (int nn = 0; nn < 16; ++nn) ks += kt[dg * 16 + nn][e];
        __syncthreads();
    }

    float* kvpp = kvp + ((size_t)bh * 8 + chunk) * 4096;
#pragma unroll
    for (int i = 0; i < 16; ++i) kvpp[(dg * 16 + i) * 64 + e] = acc[i];

    ksl[dg][e] = ks;
    __syncthreads();
    if (t < 64) ksp[((size_t)bh * 8 + chunk) * 64 + t] =
        ksl[0][t] + ksl[1][t] + ksl[2][t] + ksl[3][t];
}

// ---------------------------------------------------------------------------
// reduce 8 chunk-partials -> kvb (bf16, [d][e]) + ksum (f32)
// ---------------------------------------------------------------------------
__global__ __launch_bounds__(256) void kv_reduce(
    const float* __restrict__ kvp, const float* __restrict__ ksp,
    unsigned short* __restrict__ kvb, float* __restrict__ ksum)
{
    const int bh = blockIdx.x, t = threadIdx.x;
    const float* src = kvp + (size_t)bh * 8 * 4096;
#pragma unroll
    for (int i = 0; i < 16; ++i) {
        const int idx = i * 256 + t;
        float s = 0.f;
#pragma unroll
        for (int c = 0; c < 8; ++c) s += src[c * 4096 + idx];
        kvb[(size_t)bh * 4096 + idx] = f2bf(s);
    }
    if (t < 64) {
        float s = 0.f;
#pragma unroll
        for (int c = 0; c < 8; ++c) s += ksp[((size_t)bh * 8 + c) * 64 + t];
        ksum[bh * 64 + t] = s;
    }
}

// ---------------------------------------------------------------------------
// MT[b][c][h*64+d] = sum_e kv[b,h,d,e] * wp[c, h*64+e]   (bf16 out)
// ---------------------------------------------------------------------------
__global__ __launch_bounds__(256) void gemm_M(
    const unsigned short* __restrict__ kvb,   // [64][4096]
    const unsigned short* __restrict__ wp,    // [512][512]
    unsigned short* __restrict__ MT)          // [8][512][512]
{
    const int bh = blockIdx.x, b = bh >> 3, h = bh & 7;
    const int t = threadIdx.x, w = t >> 6, lane = t & 63;
    const int ln = lane & 15, g = lane >> 4;

    float4v acc[8][4];
#pragma unroll
    for (int i = 0; i < 8; ++i)
#pragma unroll
        for (int j = 0; j < 4; ++j) acc[i][j] = {0.f, 0.f, 0.f, 0.f};

#pragma unroll
    for (int kk = 0; kk < 2; ++kk) {
        short8v a[8], bf[4];
#pragma unroll
        for (int i = 0; i < 8; ++i)
            a[i] = *reinterpret_cast<const short8v*>(
                wp + (size_t)(w * 128 + i * 16 + ln) * 512 + h * 64 + kk * 32 + g * 8);
#pragma unroll
        for (int j = 0; j < 4; ++j)
            bf[j] = *reinterpret_cast<const short8v*>(
                kvb + (size_t)bh * 4096 + (j * 16 + ln) * 64 + kk * 32 + g * 8);
#pragma unroll
        for (int i = 0; i < 8; ++i)
#pragma unroll
            for (int j = 0; j < 4; ++j)
                acc[i][j] = __builtin_amdgcn_mfma_f32_16x16x32_bf16(a[i], bf[j], acc[i][j], 0, 0, 0);
    }

#pragma unroll
    for (int i = 0; i < 8; ++i) {
        const int c0 = w * 128 + i * 16 + g * 4;
#pragma unroll
        for (int j = 0; j < 4; ++j) {
            const int d = j * 16 + ln;
#pragma unroll
            for (int r = 0; r < 4; ++r)
                MT[(size_t)b * 262144 + (size_t)(c0 + r) * 512 + h * 64 + d] =
                    f2bf(acc[i][j][r]);
        }
    }
}

// ---------------------------------------------------------------------------
// q' = q / (q . ksum_h + eps), in place (bf16)
// ---------------------------------------------------------------------------
__global__ __launch_bounds__(256) void q_scale(
    unsigned short* __restrict__ qkv, const float* __restrict__ ksum)
{
    __shared__ float kss[512];
    const int blk = blockIdx.x;          // 1024
    const int b = blk >> 7;
    const int t = threadIdx.x;
    kss[t] = ksum[b * 512 + t];
    kss[t + 256] = ksum[b * 512 + 256 + t];
    __syncthreads();

    const int row = blk * 32 + (t >> 3);
    const int h = t & 7;
    unsigned short* p = qkv + (size_t)row * QKVC + h * 64;

    ushort8v v[8];
#pragma unroll
    for (int s = 0; s < 8; ++s) v[s] = *reinterpret_cast<const ushort8v*>(p + s * 8);

    float den = EPSF;
#pragma unroll
    for (int s = 0; s < 8; ++s)
#pragma unroll
        for (int m = 0; m < 8; ++m)
            den += bf2f(v[s][m]) * kss[h * 64 + s * 8 + m];
    const float inv = 1.0f / den;

#pragma unroll
    for (int s = 0; s < 8; ++s) {
        ushort8v o;
#pragma unroll
        for (int m = 0; m < 8; ++m) o[m] = f2bf(bf2f(v[s][m]) * inv);
        *reinterpret_cast<ushort8v*>(p + s * 8) = o;
    }
}

// ---------------------------------------------------------------------------
// out = q' @ MT_b^T + bias  (f32 out), ring-3
// ---------------------------------------------------------------------------
__global__ __launch_bounds__(512, 2) void gemm_out(
    const unsigned short* __restrict__ A,    // qkvb, lda 1536
    const unsigned short* __restrict__ Bt,   // MT [8][512][512]
    const float* __restrict__ bias,
    float* __restrict__ out)                 // [32768,512]
{
    constexpr int LDA = 1536, LDB = 512, NT = 8;
    __shared__ unsigned short ring[3][24576];

    const int t = threadIdx.x;
    const int orig = blockIdx.x;
    const int wg = (orig & 7) * 64 + (orig >> 3);   // nwg=512, %8==0
    const int bm = (wg >> 2) * 256;
    const int bn = (wg & 3) * 128;
    const unsigned short* Bm = Bt + (size_t)(bm >> 12) * 262144;

    const int w = t >> 6, lane = t & 63;
    const int ln = lane & 15, g = lane >> 4;
    const int wr = (w >> 1) * 64;
    const int wc = (w & 1) * 64;
    const int l7 = ln & 7;

    const int rs = t >> 3;
    const int ci = t & 7;
    const int swz = ci ^ (rs & 7);
    const unsigned short* As0 = A + (size_t)(bm + rs) * LDA + swz * 8;
    const unsigned short* As1 = A + (size_t)(bm + 64 + rs) * LDA + swz * 8;
    const unsigned short* As2 = A + (size_t)(bm + 128 + rs) * LDA + swz * 8;
    const unsigned short* As3 = A + (size_t)(bm + 192 + rs) * LDA + swz * 8;
    const unsigned short* Bs0 = Bm + (size_t)(bn + rs) * LDB + swz * 8;
    const unsigned short* Bs1 = Bm + (size_t)(bn + 64 + rs) * LDB + swz * 8;

#define STAGEO(Tt) do {                                                        \
        const int k0_ = (Tt) * 64;                                             \
        unsigned short* dA_ = &ring[(Tt) % 3][0];                              \
        unsigned short* dB_ = &ring[(Tt) % 3][16384];                          \
        llds16(As0 + k0_, dA_ + (size_t)t * 8);                                \
        llds16(As1 + k0_, dA_ + (size_t)(512 + t) * 8);                        \
        llds16(As2 + k0_, dA_ + (size_t)(1024 + t) * 8);                       \
        llds16(As3 + k0_, dA_ + (size_t)(1536 + t) * 8);                       \
        llds16(Bs0 + k0_, dB_ + (size_t)t * 8);                                \
        llds16(Bs1 + k0_, dB_ + (size_t)(512 + t) * 8);                        \
    } while (0)

    float4v acc[4][4];
#pragma unroll
    for (int i = 0; i < 4; ++i)
#pragma unroll
        for (int j = 0; j < 4; ++j) acc[i][j] = {0.f, 0.f, 0.f, 0.f};

    STAGEO(0);
    STAGEO(1);
    asm volatile("s_waitcnt vmcnt(6)" ::: "memory");
    __builtin_amdgcn_s_barrier();
    __builtin_amdgcn_sched_barrier(0);

#pragma unroll
    for (int T = 0; T < NT; ++T) {
        if (T + 2 < NT) STAGEO(T + 2);

        const unsigned short* base = &ring[T % 3][0];
        short8v a[4][2], b[4][2];
#pragma unroll
        for (int i = 0; i < 4; ++i)
#pragma unroll
            for (int kk = 0; kk < 2; ++kk) {
                const int row = wr + i * 16 + ln;
                a[i][kk] = *reinterpret_cast<const short8v*>(
                    base + row * 64 + (((kk * 4 + g) ^ l7) << 3));
            }
#pragma unroll
        for (int j = 0; j < 4; ++j)
#pragma unroll
            for (int kk = 0; kk < 2; ++kk) {
                const int row = wc + j * 16 + ln;
                b[j][kk] = *reinterpret_cast<const short8v*>(
                    base + 16384 + row * 64 + (((kk * 4 + g) ^ l7) << 3));
            }

        __builtin_amdgcn_s_setprio(1);
#pragma unroll
        for (int kk = 0; kk < 2; ++kk)
#pragma unroll
            for (int i = 0; i < 4; ++i)
#pragma unroll
                for (int j = 0; j < 4; ++j)
                    acc[i][j] = __builtin_amdgcn_mfma_f32_16x16x32_bf16(
                        a[i][kk], b[j][kk], acc[i][j], 0, 0, 0);
        __builtin_amdgcn_s_setprio(0);

        if (T + 1 < NT) {
            if (T + 2 < NT)
                asm volatile("s_waitcnt vmcnt(6)" ::: "memory");
            else
                asm volatile("s_waitcnt vmcnt(0)" ::: "memory");
            __builtin_amdgcn_s_barrier();
            __builtin_amdgcn_sched_barrier(0);
        }
    }
#undef STAGEO

#pragma unroll
    for (int i = 0; i < 4; ++i) {
        const int Rb = bm + wr + i * 16 + g * 4;
#pragma unroll
        for (int j = 0; j < 4; ++j) {
            const int Cc = bn + wc + j * 16 + ln;
            const float bv = bias[Cc];
#pragma unroll
            for (int r = 0; r < 4; ++r)
                out[(size_t)(Rb + r) * 512 + Cc] = acc[i][j][r] + bv;
        }
    }
}

// ---------------------------------------------------------------------------
extern "C" void kernel_launch(void* const* d_in, const int* in_sizes, int n_in,
                              void* d_out, int out_size, void* d_ws, size_t ws_size,
                              hipStream_t stream)
{
    const float* x      = (const float*)d_in[0];  // [8,4096,512]
    const float* w_qkv  = (const float*)d_in[1];  // [1536,512]
    const float* w_proj = (const float*)d_in[2];  // [512,512]
    const float* b_proj = (const float*)d_in[3];  // [512]
    float* out = (float*)d_out;

    char* ws = (char*)d_ws;
    unsigned short* qkvb = (unsigned short*)ws;                    // 96 MiB
    size_t off = (size_t)32768 * 1536 * 2;
    unsigned short* wqb  = (unsigned short*)(ws + off); off += (size_t)1536 * 512 * 2;
    unsigned short* wpb  = (unsigned short*)(ws + off); off += (size_t)512 * 512 * 2;
    float* kvp           = (float*)(ws + off);          off += (size_t)64 * 8 * 4096 * 4;
    float* ksp           = (float*)(ws + off);          off += (size_t)64 * 8 * 64 * 4;
    unsigned short* kvb  = (unsigned short*)(ws + off); off += (size_t)64 * 4096 * 2;
    float* ksumb         = (float*)(ws + off);          off += (size_t)64 * 64 * 4;
    unsigned short* MT   = (unsigned short*)(ws + off); off += (size_t)8 * 512 * 512 * 2;

    // 1) convert weights to bf16 (x is consumed as f32 directly by gemm_qkv)
    cvt_weights<<<dim3(((1536 * 512 + 512 * 512) / 8 + 255) / 256), dim3(256), 0, stream>>>(
        w_qkv, w_proj, wqb, wpb);

    // 2) qkv = elu1(x @ w_qkv^T), fused f32->bf16 A-staging — ring-3
    gemm_qkv<<<dim3(1536), dim3(512), 0, stream>>>(x, wqb, qkvb);

    // 3) kv partials (v1) + reduce
    kv_part<<<dim3(64, 8), dim3(256), 0, stream>>>(qkvb, kvp, ksp);
    kv_reduce<<<dim3(64), dim3(256), 0, stream>>>(kvp, ksp, kvb, ksumb);

    // 4) MT_b = (kv_h @ wp_h^T) stacked, per batch
    gemm_M<<<dim3(64), dim3(256), 0, stream>>>(kvb, wpb, MT);

    // 5) q' = q / (q.ksum + eps), in place
    q_scale<<<dim3(1024), dim3(256), 0, stream>>>(qkvb, ksumb);

    // 6) out = q' @ MT_b^T + bias (f32) — ring-3
    gemm_out<<<dim3(512), dim3(512), 0, stream>>>(qkvb, MT, b_proj, out);
}

// Round 14
// 181.161 us; speedup vs baseline: 1.1234x; 1.0885x over previous
//
#include <hip/hip_runtime.h>
#include <hip/hip_bf16.h>
#include <math.h>

#define EPSF 1e-6f

constexpr int Bc = 8;
constexpr int Nc = 4096;
constexpr int Dc = 512;
constexpr int QKVC = 3 * Dc;  // 1536

typedef __attribute__((ext_vector_type(8))) short short8v;
typedef __attribute__((ext_vector_type(8))) unsigned short ushort8v;
typedef __attribute__((ext_vector_type(4))) float float4v;

__device__ __forceinline__ unsigned short f2bf(float f) {
    union { float f; unsigned int u; } v; v.f = f;
    unsigned int u = v.u;
    return (unsigned short)((u + 0x7fffu + ((u >> 16) & 1u)) >> 16);
}
__device__ __forceinline__ float bf2f(unsigned short h) {
    union { unsigned int u; float f; } v; v.u = ((unsigned int)h) << 16;
    return v.f;
}

typedef __attribute__((address_space(1))) const void gvoid_t;
typedef __attribute__((address_space(3))) void lvoid_t;
__device__ __forceinline__ void llds16(const void* g, void* l) {
    __builtin_amdgcn_global_load_lds((gvoid_t*)g, (lvoid_t*)l, 16, 0, 0);
}

// ---------------------------------------------------------------------------
// f32 -> bf16 conversion, 8 elems/thread
// ---------------------------------------------------------------------------
__global__ __launch_bounds__(256) void cvt_f32_bf16(
    const float* __restrict__ in, unsigned short* __restrict__ out, int n8)
{
    int i = blockIdx.x * 256 + threadIdx.x;
    if (i >= n8) return;
    float4 a = reinterpret_cast<const float4*>(in)[2 * i];
    float4 b = reinterpret_cast<const float4*>(in)[2 * i + 1];
    ushort8v o;
    o[0] = f2bf(a.x); o[1] = f2bf(a.y); o[2] = f2bf(a.z); o[3] = f2bf(a.w);
    o[4] = f2bf(b.x); o[5] = f2bf(b.y); o[6] = f2bf(b.z); o[7] = f2bf(b.w);
    reinterpret_cast<ushort8v*>(out)[i] = o;
}

// combined weight convert: w_qkv (1536x512) then w_proj (512x512)
__global__ __launch_bounds__(256) void cvt_weights(
    const float* __restrict__ wq, const float* __restrict__ wp,
    unsigned short* __restrict__ wqo, unsigned short* __restrict__ wpo)
{
    const int i = blockIdx.x * 256 + threadIdx.x;
    const int NQ = 1536 * 512 / 8;            // 98304
    const float* src; unsigned short* dst; int idx;
    if (i < NQ) { src = wq; dst = wqo; idx = i; }
    else        { src = wp; dst = wpo; idx = i - NQ; }
    float4 a = reinterpret_cast<const float4*>(src)[2 * idx];
    float4 b = reinterpret_cast<const float4*>(src)[2 * idx + 1];
    ushort8v o;
    o[0] = f2bf(a.x); o[1] = f2bf(a.y); o[2] = f2bf(a.z); o[3] = f2bf(a.w);
    o[4] = f2bf(b.x); o[5] = f2bf(b.y); o[6] = f2bf(b.z); o[7] = f2bf(b.w);
    reinterpret_cast<ushort8v*>(dst)[idx] = o;
}

// ---------------------------------------------------------------------------
// qkv GEMM (ring-3, best measured: 83us, conflicts=0) — round-11 verbatim
// ---------------------------------------------------------------------------
__global__ __launch_bounds__(512, 2) void gemm_qkv(
    const unsigned short* __restrict__ A,    // [32768,512]
    const unsigned short* __restrict__ Bm,   // [1536,512]
    unsigned short* __restrict__ Cout)       // [32768,1536]
{
    constexpr int LDA = 512, LDB = 512, LDC = 1536;
    constexpr int NT = 8;
    __shared__ unsigned short ring[3][24576];

    const int t = threadIdx.x;
    const int orig = blockIdx.x;
    const int wg = (orig & 7) * 192 + (orig >> 3);   // nwg=1536, %8==0
    const int bm = (wg / 12) * 256;
    const int bn = (wg % 12) * 128;

    const int w = t >> 6, lane = t & 63;
    const int ln = lane & 15, g = lane >> 4;
    const int wr = (w >> 1) * 64;
    const int wc = (w & 1) * 64;
    const int l7 = ln & 7;

    const int rs = t >> 3;
    const int ci = t & 7;
    const int swz = ci ^ (rs & 7);
    const unsigned short* As0 = A + (size_t)(bm + rs) * LDA + swz * 8;
    const unsigned short* As1 = A + (size_t)(bm + 64 + rs) * LDA + swz * 8;
    const unsigned short* As2 = A + (size_t)(bm + 128 + rs) * LDA + swz * 8;
    const unsigned short* As3 = A + (size_t)(bm + 192 + rs) * LDA + swz * 8;
    const unsigned short* Bs0 = Bm + (size_t)(bn + rs) * LDB + swz * 8;
    const unsigned short* Bs1 = Bm + (size_t)(bn + 64 + rs) * LDB + swz * 8;

#define STAGEQ(Tt) do {                                                        \
        const int k0_ = (Tt) * 64;                                             \
        unsigned short* dA_ = &ring[(Tt) % 3][0];                              \
        unsigned short* dB_ = &ring[(Tt) % 3][16384];                          \
        llds16(As0 + k0_, dA_ + (size_t)t * 8);                                \
        llds16(As1 + k0_, dA_ + (size_t)(512 + t) * 8);                        \
        llds16(As2 + k0_, dA_ + (size_t)(1024 + t) * 8);                       \
        llds16(As3 + k0_, dA_ + (size_t)(1536 + t) * 8);                       \
        llds16(Bs0 + k0_, dB_ + (size_t)t * 8);                                \
        llds16(Bs1 + k0_, dB_ + (size_t)(512 + t) * 8);                        \
    } while (0)

    float4v acc[4][4];
#pragma unroll
    for (int i = 0; i < 4; ++i)
#pragma unroll
        for (int j = 0; j < 4; ++j) acc[i][j] = {0.f, 0.f, 0.f, 0.f};

    STAGEQ(0);
    STAGEQ(1);
    asm volatile("s_waitcnt vmcnt(6)" ::: "memory");
    __builtin_amdgcn_s_barrier();
    __builtin_amdgcn_sched_barrier(0);

#pragma unroll
    for (int T = 0; T < NT; ++T) {
        if (T + 2 < NT) STAGEQ(T + 2);

        const unsigned short* base = &ring[T % 3][0];
        short8v a[4][2], b[4][2];
#pragma unroll
        for (int i = 0; i < 4; ++i)
#pragma unroll
            for (int kk = 0; kk < 2; ++kk) {
                const int row = wr + i * 16 + ln;
                a[i][kk] = *reinterpret_cast<const short8v*>(
                    base + row * 64 + (((kk * 4 + g) ^ l7) << 3));
            }
#pragma unroll
        for (int j = 0; j < 4; ++j)
#pragma unroll
            for (int kk = 0; kk < 2; ++kk) {
                const int row = wc + j * 16 + ln;
                b[j][kk] = *reinterpret_cast<const short8v*>(
                    base + 16384 + row * 64 + (((kk * 4 + g) ^ l7) << 3));
            }

        __builtin_amdgcn_s_setprio(1);
#pragma unroll
        for (int kk = 0; kk < 2; ++kk)
#pragma unroll
            for (int i = 0; i < 4; ++i)
#pragma unroll
                for (int j = 0; j < 4; ++j)
                    acc[i][j] = __builtin_amdgcn_mfma_f32_16x16x32_bf16(
                        a[i][kk], b[j][kk], acc[i][j], 0, 0, 0);
        __builtin_amdgcn_s_setprio(0);

        if (T + 1 < NT) {
            if (T + 2 < NT)
                asm volatile("s_waitcnt vmcnt(6)" ::: "memory");
            else
                asm volatile("s_waitcnt vmcnt(0)" ::: "memory");
            __builtin_amdgcn_s_barrier();
            __builtin_amdgcn_sched_barrier(0);
        }
    }
#undef STAGEQ

#pragma unroll
    for (int i = 0; i < 4; ++i) {
        const int Rb = bm + wr + i * 16 + g * 4;
#pragma unroll
        for (int j = 0; j < 4; ++j) {
            const int Cc = bn + wc + j * 16 + ln;
            const bool do_elu = (Cc < 1024);
#pragma unroll
            for (int r = 0; r < 4; ++r) {
                float v = acc[i][j][r];
                if (do_elu) v = (v > 0.f) ? (v + 1.0f + EPSF) : (expf(v) + EPSF);
                Cout[(size_t)(Rb + r) * LDC + Cc] = f2bf(v);
            }
        }
    }
}

// ---------------------------------------------------------------------------
// kv partials v3: v1 staging VERBATIM (f32 [n][d] padded tiles, dbuf-free
// proven structure); compute remapped to (di,ej) 4x4 outer product so both
// LDS reads per nn are per-lane b128 (320 -> 128 LDS issues/wave/tile).
// Accumulation order per (d,e) is n-ascending, bit-identical to v1.
// ---------------------------------------------------------------------------
__global__ __launch_bounds__(256) void kv_part(
    const unsigned short* __restrict__ qkv,
    float* __restrict__ kvp, float* __restrict__ ksp)
{
    const int bh = blockIdx.x, chunk = blockIdx.y;
    const int b = bh >> 3, h = bh & 7;

    __shared__ float kt[64][68];
    __shared__ float vt[64][68];
    __shared__ float ksl[4][64];

    const int t  = threadIdx.x;
    const int e  = t & 63, dg = t >> 6;      // for ksum (v1 mapping)
    const int rr = t >> 3, slot = t & 7;     // staging (v1 mapping)
    const int di = t >> 4, ej = t & 15;      // compute: d=di*4.., e=ej*4..

    float acc[4][4] = {};
    float ks = 0.f;

    const size_t base = ((size_t)b * Nc + (size_t)chunk * 512) * QKVC + h * 64;

    for (int n0 = 0; n0 < 512; n0 += 64) {
#pragma unroll
        for (int half = 0; half < 2; ++half) {
            const int row = rr + half * 32;
            const unsigned short* kr = qkv + base + (size_t)(n0 + row) * QKVC + Dc + slot * 8;
            const unsigned short* vr = kr + Dc;
            ushort8v kq = *reinterpret_cast<const ushort8v*>(kr);
            ushort8v vq = *reinterpret_cast<const ushort8v*>(vr);
            float4 k0 = make_float4(bf2f(kq[0]), bf2f(kq[1]), bf2f(kq[2]), bf2f(kq[3]));
            float4 k1 = make_float4(bf2f(kq[4]), bf2f(kq[5]), bf2f(kq[6]), bf2f(kq[7]));
            float4 v0 = make_float4(bf2f(vq[0]), bf2f(vq[1]), bf2f(vq[2]), bf2f(vq[3]));
            float4 v1 = make_float4(bf2f(vq[4]), bf2f(vq[5]), bf2f(vq[6]), bf2f(vq[7]));
            *reinterpret_cast<float4*>(&kt[row][slot * 8])     = k0;
            *reinterpret_cast<float4*>(&kt[row][slot * 8 + 4]) = k1;
            *reinterpret_cast<float4*>(&vt[row][slot * 8])     = v0;
            *reinterpret_cast<float4*>(&vt[row][slot * 8 + 4]) = v1;
        }
        __syncthreads();

        // outer-product compute: 2 b128 reads + 16 FMA per nn
#pragma unroll 4
        for (int nn = 0; nn < 64; ++nn) {
            const float4 kd = *reinterpret_cast<const float4*>(&kt[nn][di * 4]);
            const float4 ve = *reinterpret_cast<const float4*>(&vt[nn][ej * 4]);
            acc[0][0] += kd.x * ve.x; acc[0][1] += kd.x * ve.y;
            acc[0][2] += kd.x * ve.z; acc[0][3] += kd.x * ve.w;
            acc[1][0] += kd.y * ve.x; acc[1][1] += kd.y * ve.y;
            acc[1][2] += kd.y * ve.z; acc[1][3] += kd.y * ve.w;
            acc[2][0] += kd.z * ve.x; acc[2][1] += kd.z * ve.y;
            acc[2][2] += kd.z * ve.z; acc[2][3] += kd.z * ve.w;
            acc[3][0] += kd.w * ve.x; acc[3][1] += kd.w * ve.y;
            acc[3][2] += kd.w * ve.z; acc[3][3] += kd.w * ve.w;
        }
#pragma unroll
        for (int nn = 0; nn < 16; ++nn) ks += kt[dg * 16 + nn][e];
        __syncthreads();
    }

    float* kvpp = kvp + ((size_t)bh * 8 + chunk) * 4096;
#pragma unroll
    for (int i = 0; i < 4; ++i) {
        float4 row = make_float4(acc[i][0], acc[i][1], acc[i][2], acc[i][3]);
        *reinterpret_cast<float4*>(kvpp + (di * 4 + i) * 64 + ej * 4) = row;
    }

    ksl[dg][e] = ks;
    __syncthreads();
    if (t < 64) ksp[((size_t)bh * 8 + chunk) * 64 + t] =
        ksl[0][t] + ksl[1][t] + ksl[2][t] + ksl[3][t];
}

// ---------------------------------------------------------------------------
// reduce 8 chunk-partials -> kvb (bf16, [d][e]) + ksum (f32)
// ---------------------------------------------------------------------------
__global__ __launch_bounds__(256) void kv_reduce(
    const float* __restrict__ kvp, const float* __restrict__ ksp,
    unsigned short* __restrict__ kvb, float* __restrict__ ksum)
{
    const int bh = blockIdx.x, t = threadIdx.x;
    const float* src = kvp + (size_t)bh * 8 * 4096;
#pragma unroll
    for (int i = 0; i < 16; ++i) {
        const int idx = i * 256 + t;
        float s = 0.f;
#pragma unroll
        for (int c = 0; c < 8; ++c) s += src[c * 4096 + idx];
        kvb[(size_t)bh * 4096 + idx] = f2bf(s);
    }
    if (t < 64) {
        float s = 0.f;
#pragma unroll
        for (int c = 0; c < 8; ++c) s += ksp[((size_t)bh * 8 + c) * 64 + t];
        ksum[bh * 64 + t] = s;
    }
}

// ---------------------------------------------------------------------------
// MT[b][c][h*64+d] = sum_e kv[b,h,d,e] * wp[c, h*64+e]   (bf16 out)
// ---------------------------------------------------------------------------
__global__ __launch_bounds__(256) void gemm_M(
    const unsigned short* __restrict__ kvb,   // [64][4096]
    const unsigned short* __restrict__ wp,    // [512][512]
    unsigned short* __restrict__ MT)          // [8][512][512]
{
    const int bh = blockIdx.x, b = bh >> 3, h = bh & 7;
    const int t = threadIdx.x, w = t >> 6, lane = t & 63;
    const int ln = lane & 15, g = lane >> 4;

    float4v acc[8][4];
#pragma unroll
    for (int i = 0; i < 8; ++i)
#pragma unroll
        for (int j = 0; j < 4; ++j) acc[i][j] = {0.f, 0.f, 0.f, 0.f};

#pragma unroll
    for (int kk = 0; kk < 2; ++kk) {
        short8v a[8], bf[4];
#pragma unroll
        for (int i = 0; i < 8; ++i)
            a[i] = *reinterpret_cast<const short8v*>(
                wp + (size_t)(w * 128 + i * 16 + ln) * 512 + h * 64 + kk * 32 + g * 8);
#pragma unroll
        for (int j = 0; j < 4; ++j)
            bf[j] = *reinterpret_cast<const short8v*>(
                kvb + (size_t)bh * 4096 + (j * 16 + ln) * 64 + kk * 32 + g * 8);
#pragma unroll
        for (int i = 0; i < 8; ++i)
#pragma unroll
            for (int j = 0; j < 4; ++j)
                acc[i][j] = __builtin_amdgcn_mfma_f32_16x16x32_bf16(a[i], bf[j], acc[i][j], 0, 0, 0);
    }

#pragma unroll
    for (int i = 0; i < 8; ++i) {
        const int c0 = w * 128 + i * 16 + g * 4;
#pragma unroll
        for (int j = 0; j < 4; ++j) {
            const int d = j * 16 + ln;
#pragma unroll
            for (int r = 0; r < 4; ++r)
                MT[(size_t)b * 262144 + (size_t)(c0 + r) * 512 + h * 64 + d] =
                    f2bf(acc[i][j][r]);
        }
    }
}

// ---------------------------------------------------------------------------
// q' = q / (q . ksum_h + eps), in place (bf16)
// ---------------------------------------------------------------------------
__global__ __launch_bounds__(256) void q_scale(
    unsigned short* __restrict__ qkv, const float* __restrict__ ksum)
{
    __shared__ float kss[512];
    const int blk = blockIdx.x;          // 1024
    const int b = blk >> 7;
    const int t = threadIdx.x;
    kss[t] = ksum[b * 512 + t];
    kss[t + 256] = ksum[b * 512 + 256 + t];
    __syncthreads();

    const int row = blk * 32 + (t >> 3);
    const int h = t & 7;
    unsigned short* p = qkv + (size_t)row * QKVC + h * 64;

    ushort8v v[8];
#pragma unroll
    for (int s = 0; s < 8; ++s) v[s] = *reinterpret_cast<const ushort8v*>(p + s * 8);

    float den = EPSF;
#pragma unroll
    for (int s = 0; s < 8; ++s)
#pragma unroll
        for (int m = 0; m < 8; ++m)
            den += bf2f(v[s][m]) * kss[h * 64 + s * 8 + m];
    const float inv = 1.0f / den;

#pragma unroll
    for (int s = 0; s < 8; ++s) {
        ushort8v o;
#pragma unroll
        for (int m = 0; m < 8; ++m) o[m] = f2bf(bf2f(v[s][m]) * inv);
        *reinterpret_cast<ushort8v*>(p + s * 8) = o;
    }
}

// ---------------------------------------------------------------------------
// out = q' @ MT_b^T + bias  (f32 out), ring-3
// ---------------------------------------------------------------------------
__global__ __launch_bounds__(512, 2) void gemm_out(
    const unsigned short* __restrict__ A,    // qkvb, lda 1536
    const unsigned short* __restrict__ Bt,   // MT [8][512][512]
    const float* __restrict__ bias,
    float* __restrict__ out)                 // [32768,512]
{
    constexpr int LDA = 1536, LDB = 512, NT = 8;
    __shared__ unsigned short ring[3][24576];

    const int t = threadIdx.x;
    const int orig = blockIdx.x;
    const int wg = (orig & 7) * 64 + (orig >> 3);   // nwg=512, %8==0
    const int bm = (wg >> 2) * 256;
    const int bn = (wg & 3) * 128;
    const unsigned short* Bm = Bt + (size_t)(bm >> 12) * 262144;

    const int w = t >> 6, lane = t & 63;
    const int ln = lane & 15, g = lane >> 4;
    const int wr = (w >> 1) * 64;
    const int wc = (w & 1) * 64;
    const int l7 = ln & 7;

    const int rs = t >> 3;
    const int ci = t & 7;
    const int swz = ci ^ (rs & 7);
    const unsigned short* As0 = A + (size_t)(bm + rs) * LDA + swz * 8;
    const unsigned short* As1 = A + (size_t)(bm + 64 + rs) * LDA + swz * 8;
    const unsigned short* As2 = A + (size_t)(bm + 128 + rs) * LDA + swz * 8;
    const unsigned short* As3 = A + (size_t)(bm + 192 + rs) * LDA + swz * 8;
    const unsigned short* Bs0 = Bm + (size_t)(bn + rs) * LDB + swz * 8;
    const unsigned short* Bs1 = Bm + (size_t)(bn + 64 + rs) * LDB + swz * 8;

#define STAGEO(Tt) do {                                                        \
        const int k0_ = (Tt) * 64;                                             \
        unsigned short* dA_ = &ring[(Tt) % 3][0];                              \
        unsigned short* dB_ = &ring[(Tt) % 3][16384];                          \
        llds16(As0 + k0_, dA_ + (size_t)t * 8);                                \
        llds16(As1 + k0_, dA_ + (size_t)(512 + t) * 8);                        \
        llds16(As2 + k0_, dA_ + (size_t)(1024 + t) * 8);                       \
        llds16(As3 + k0_, dA_ + (size_t)(1536 + t) * 8);                       \
        llds16(Bs0 + k0_, dB_ + (size_t)t * 8);                                \
        llds16(Bs1 + k0_, dB_ + (size_t)(512 + t) * 8);                        \
    } while (0)

    float4v acc[4][4];
#pragma unroll
    for (int i = 0; i < 4; ++i)
#pragma unroll
        for (int j = 0; j < 4; ++j) acc[i][j] = {0.f, 0.f, 0.f, 0.f};

    STAGEO(0);
    STAGEO(1);
    asm volatile("s_waitcnt vmcnt(6)" ::: "memory");
    __builtin_amdgcn_s_barrier();
    __builtin_amdgcn_sched_barrier(0);

#pragma unroll
    for (int T = 0; T < NT; ++T) {
        if (T + 2 < NT) STAGEO(T + 2);

        const unsigned short* base = &ring[T % 3][0];
        short8v a[4][2], b[4][2];
#pragma unroll
        for (int i = 0; i < 4; ++i)
#pragma unroll
            for (int kk = 0; kk < 2; ++kk) {
                const int row = wr + i * 16 + ln;
                a[i][kk] = *reinterpret_cast<const short8v*>(
                    base + row * 64 + (((kk * 4 + g) ^ l7) << 3));
            }
#pragma unroll
        for (int j = 0; j < 4; ++j)
#pragma unroll
            for (int kk = 0; kk < 2; ++kk) {
                const int row = wc + j * 16 + ln;
                b[j][kk] = *reinterpret_cast<const short8v*>(
                    base + 16384 + row * 64 + (((kk * 4 + g) ^ l7) << 3));
            }

        __builtin_amdgcn_s_setprio(1);
#pragma unroll
        for (int kk = 0; kk < 2; ++kk)
#pragma unroll
            for (int i = 0; i < 4; ++i)
#pragma unroll
                for (int j = 0; j < 4; ++j)
                    acc[i][j] = __builtin_amdgcn_mfma_f32_16x16x32_bf16(
                        a[i][kk], b[j][kk], acc[i][j], 0, 0, 0);
        __builtin_amdgcn_s_setprio(0);

        if (T + 1 < NT) {
            if (T + 2 < NT)
                asm volatile("s_waitcnt vmcnt(6)" ::: "memory");
            else
                asm volatile("s_waitcnt vmcnt(0)" ::: "memory");
            __builtin_amdgcn_s_barrier();
            __builtin_amdgcn_sched_barrier(0);
        }
    }
#undef STAGEO

#pragma unroll
    for (int i = 0; i < 4; ++i) {
        const int Rb = bm + wr + i * 16 + g * 4;
#pragma unroll
        for (int j = 0; j < 4; ++j) {
            const int Cc = bn + wc + j * 16 + ln;
            const float bv = bias[Cc];
#pragma unroll
            for (int r = 0; r < 4; ++r)
                out[(size_t)(Rb + r) * 512 + Cc] = acc[i][j][r] + bv;
        }
    }
}

// ---------------------------------------------------------------------------
extern "C" void kernel_launch(void* const* d_in, const int* in_sizes, int n_in,
                              void* d_out, int out_size, void* d_ws, size_t ws_size,
                              hipStream_t stream)
{
    const float* x      = (const float*)d_in[0];  // [8,4096,512]
    const float* w_qkv  = (const float*)d_in[1];  // [1536,512]
    const float* w_proj = (const float*)d_in[2];  // [512,512]
    const float* b_proj = (const float*)d_in[3];  // [512]
    float* out = (float*)d_out;

    char* ws = (char*)d_ws;
    unsigned short* qkvb = (unsigned short*)ws;                    // 96 MiB
    size_t off = (size_t)32768 * 1536 * 2;
    unsigned short* xb   = (unsigned short*)(ws + off); off += (size_t)32768 * 512 * 2;
    unsigned short* wqb  = (unsigned short*)(ws + off); off += (size_t)1536 * 512 * 2;
    unsigned short* wpb  = (unsigned short*)(ws + off); off += (size_t)512 * 512 * 2;
    float* kvp           = (float*)(ws + off);          off += (size_t)64 * 8 * 4096 * 4;
    float* ksp           = (float*)(ws + off);          off += (size_t)64 * 8 * 64 * 4;
    unsigned short* kvb  = (unsigned short*)(ws + off); off += (size_t)64 * 4096 * 2;
    float* ksumb         = (float*)(ws + off);          off += (size_t)64 * 64 * 4;
    unsigned short* MT   = (unsigned short*)(ws + off); off += (size_t)8 * 512 * 512 * 2;

    // 1) convert inputs to bf16
    cvt_f32_bf16<<<dim3((32768 * 512 / 8 + 255) / 256), dim3(256), 0, stream>>>(x, xb, 32768 * 512 / 8);
    cvt_weights<<<dim3(((1536 * 512 + 512 * 512) / 8 + 255) / 256), dim3(256), 0, stream>>>(
        w_qkv, w_proj, wqb, wpb);

    // 2) qkv = elu1(x @ w_qkv^T) (elu on cols<1024), bf16 out — ring-3
    gemm_qkv<<<dim3(1536), dim3(512), 0, stream>>>(xb, wqb, qkvb);

    // 3) kv partials (v3: v1 staging + outer-product compute) + reduce
    kv_part<<<dim3(64, 8), dim3(256), 0, stream>>>(qkvb, kvp, ksp);
    kv_reduce<<<dim3(64), dim3(256), 0, stream>>>(kvp, ksp, kvb, ksumb);

    // 4) MT_b = (kv_h @ wp_h^T) stacked, per batch
    gemm_M<<<dim3(64), dim3(256), 0, stream>>>(kvb, wpb, MT);

    // 5) q' = q / (q.ksum + eps), in place
    q_scale<<<dim3(1024), dim3(256), 0, stream>>>(qkvb, ksumb);

    // 6) out = q' @ MT_b^T + bias (f32) — ring-3
    gemm_out<<<dim3(512), dim3(512), 0, stream>>>(qkvb, MT, b_proj, out);
}

// Round 15
// 166.326 us; speedup vs baseline: 1.2236x; 1.0892x over previous
//
#include <hip/hip_runtime.h>
#include <hip/hip_bf16.h>
#include <math.h>

#define EPSF 1e-6f

constexpr int Bc = 8;
constexpr int Nc = 4096;
constexpr int Dc = 512;
constexpr int QKVC = 3 * Dc;  // 1536

typedef __attribute__((ext_vector_type(8))) short short8v;
typedef __attribute__((ext_vector_type(8))) unsigned short ushort8v;
typedef __attribute__((ext_vector_type(4))) float float4v;

__device__ __forceinline__ unsigned short f2bf(float f) {
    union { float f; unsigned int u; } v; v.f = f;
    unsigned int u = v.u;
    return (unsigned short)((u + 0x7fffu + ((u >> 16) & 1u)) >> 16);
}
__device__ __forceinline__ float bf2f(unsigned short h) {
    union { unsigned int u; float f; } v; v.u = ((unsigned int)h) << 16;
    return v.f;
}

typedef __attribute__((address_space(1))) const void gvoid_t;
typedef __attribute__((address_space(3))) void lvoid_t;
__device__ __forceinline__ void llds16(const void* g, void* l) {
    __builtin_amdgcn_global_load_lds((gvoid_t*)g, (lvoid_t*)l, 16, 0, 0);
}

// ---------------------------------------------------------------------------
// f32 -> bf16 conversion, 8 elems/thread
// ---------------------------------------------------------------------------
__global__ __launch_bounds__(256) void cvt_f32_bf16(
    const float* __restrict__ in, unsigned short* __restrict__ out, int n8)
{
    int i = blockIdx.x * 256 + threadIdx.x;
    if (i >= n8) return;
    float4 a = reinterpret_cast<const float4*>(in)[2 * i];
    float4 b = reinterpret_cast<const float4*>(in)[2 * i + 1];
    ushort8v o;
    o[0] = f2bf(a.x); o[1] = f2bf(a.y); o[2] = f2bf(a.z); o[3] = f2bf(a.w);
    o[4] = f2bf(b.x); o[5] = f2bf(b.y); o[6] = f2bf(b.z); o[7] = f2bf(b.w);
    reinterpret_cast<ushort8v*>(out)[i] = o;
}

// combined weight convert: w_qkv (1536x512) then w_proj (512x512)
__global__ __launch_bounds__(256) void cvt_weights(
    const float* __restrict__ wq, const float* __restrict__ wp,
    unsigned short* __restrict__ wqo, unsigned short* __restrict__ wpo)
{
    const int i = blockIdx.x * 256 + threadIdx.x;
    const int NQ = 1536 * 512 / 8;            // 98304
    const float* src; unsigned short* dst; int idx;
    if (i < NQ) { src = wq; dst = wqo; idx = i; }
    else        { src = wp; dst = wpo; idx = i - NQ; }
    float4 a = reinterpret_cast<const float4*>(src)[2 * idx];
    float4 b = reinterpret_cast<const float4*>(src)[2 * idx + 1];
    ushort8v o;
    o[0] = f2bf(a.x); o[1] = f2bf(a.y); o[2] = f2bf(a.z); o[3] = f2bf(a.w);
    o[4] = f2bf(b.x); o[5] = f2bf(b.y); o[6] = f2bf(b.z); o[7] = f2bf(b.w);
    reinterpret_cast<ushort8v*>(dst)[idx] = o;
}

// ---------------------------------------------------------------------------
// qkv GEMM (ring-3, best measured: 83us, conflicts=0) — round-11 verbatim
// ---------------------------------------------------------------------------
__global__ __launch_bounds__(512, 2) void gemm_qkv(
    const unsigned short* __restrict__ A,    // [32768,512]
    const unsigned short* __restrict__ Bm,   // [1536,512]
    unsigned short* __restrict__ Cout)       // [32768,1536]
{
    constexpr int LDA = 512, LDB = 512, LDC = 1536;
    constexpr int NT = 8;
    __shared__ unsigned short ring[3][24576];

    const int t = threadIdx.x;
    const int orig = blockIdx.x;
    const int wg = (orig & 7) * 192 + (orig >> 3);   // nwg=1536, %8==0
    const int bm = (wg / 12) * 256;
    const int bn = (wg % 12) * 128;

    const int w = t >> 6, lane = t & 63;
    const int ln = lane & 15, g = lane >> 4;
    const int wr = (w >> 1) * 64;
    const int wc = (w & 1) * 64;
    const int l7 = ln & 7;

    const int rs = t >> 3;
    const int ci = t & 7;
    const int swz = ci ^ (rs & 7);
    const unsigned short* As0 = A + (size_t)(bm + rs) * LDA + swz * 8;
    const unsigned short* As1 = A + (size_t)(bm + 64 + rs) * LDA + swz * 8;
    const unsigned short* As2 = A + (size_t)(bm + 128 + rs) * LDA + swz * 8;
    const unsigned short* As3 = A + (size_t)(bm + 192 + rs) * LDA + swz * 8;
    const unsigned short* Bs0 = Bm + (size_t)(bn + rs) * LDB + swz * 8;
    const unsigned short* Bs1 = Bm + (size_t)(bn + 64 + rs) * LDB + swz * 8;

#define STAGEQ(Tt) do {                                                        \
        const int k0_ = (Tt) * 64;                                             \
        unsigned short* dA_ = &ring[(Tt) % 3][0];                              \
        unsigned short* dB_ = &ring[(Tt) % 3][16384];                          \
        llds16(As0 + k0_, dA_ + (size_t)t * 8);                                \
        llds16(As1 + k0_, dA_ + (size_t)(512 + t) * 8);                        \
        llds16(As2 + k0_, dA_ + (size_t)(1024 + t) * 8);                       \
        llds16(As3 + k0_, dA_ + (size_t)(1536 + t) * 8);                       \
        llds16(Bs0 + k0_, dB_ + (size_t)t * 8);                                \
        llds16(Bs1 + k0_, dB_ + (size_t)(512 + t) * 8);                        \
    } while (0)

    float4v acc[4][4];
#pragma unroll
    for (int i = 0; i < 4; ++i)
#pragma unroll
        for (int j = 0; j < 4; ++j) acc[i][j] = {0.f, 0.f, 0.f, 0.f};

    STAGEQ(0);
    STAGEQ(1);
    asm volatile("s_waitcnt vmcnt(6)" ::: "memory");
    __builtin_amdgcn_s_barrier();
    __builtin_amdgcn_sched_barrier(0);

#pragma unroll
    for (int T = 0; T < NT; ++T) {
        if (T + 2 < NT) STAGEQ(T + 2);

        const unsigned short* base = &ring[T % 3][0];
        short8v a[4][2], b[4][2];
#pragma unroll
        for (int i = 0; i < 4; ++i)
#pragma unroll
            for (int kk = 0; kk < 2; ++kk) {
                const int row = wr + i * 16 + ln;
                a[i][kk] = *reinterpret_cast<const short8v*>(
                    base + row * 64 + (((kk * 4 + g) ^ l7) << 3));
            }
#pragma unroll
        for (int j = 0; j < 4; ++j)
#pragma unroll
            for (int kk = 0; kk < 2; ++kk) {
                const int row = wc + j * 16 + ln;
                b[j][kk] = *reinterpret_cast<const short8v*>(
                    base + 16384 + row * 64 + (((kk * 4 + g) ^ l7) << 3));
            }

        __builtin_amdgcn_s_setprio(1);
#pragma unroll
        for (int kk = 0; kk < 2; ++kk)
#pragma unroll
            for (int i = 0; i < 4; ++i)
#pragma unroll
                for (int j = 0; j < 4; ++j)
                    acc[i][j] = __builtin_amdgcn_mfma_f32_16x16x32_bf16(
                        a[i][kk], b[j][kk], acc[i][j], 0, 0, 0);
        __builtin_amdgcn_s_setprio(0);

        if (T + 1 < NT) {
            if (T + 2 < NT)
                asm volatile("s_waitcnt vmcnt(6)" ::: "memory");
            else
                asm volatile("s_waitcnt vmcnt(0)" ::: "memory");
            __builtin_amdgcn_s_barrier();
            __builtin_amdgcn_sched_barrier(0);
        }
    }
#undef STAGEQ

#pragma unroll
    for (int i = 0; i < 4; ++i) {
        const int Rb = bm + wr + i * 16 + g * 4;
#pragma unroll
        for (int j = 0; j < 4; ++j) {
            const int Cc = bn + wc + j * 16 + ln;
            const bool do_elu = (Cc < 1024);
#pragma unroll
            for (int r = 0; r < 4; ++r) {
                float v = acc[i][j][r];
                if (do_elu) v = (v > 0.f) ? (v + 1.0f + EPSF) : (expf(v) + EPSF);
                Cout[(size_t)(Rb + r) * LDC + Cc] = f2bf(v);
            }
        }
    }
}

// ---------------------------------------------------------------------------
// kv partials v4: MFMA. Stage TRANSPOSED bf16 tiles ktT[d][n], vtT[e][n]
// (pad 72 -> 144B rows, 16B-aligned b128 reads, 2-way/free). kv = K^T V via
// mfma(A=ktT rows d, B=vtT rows e, contraction n). v2's proven reg-transpose
// staging (no cvt: stays bf16); v2's proven ksum path. 1-deep stage->barrier->
// compute structure (v1-proven).
// ---------------------------------------------------------------------------
__global__ __launch_bounds__(256) void kv_part(
    const unsigned short* __restrict__ qkv,
    float* __restrict__ kvp, float* __restrict__ ksp)
{
    const int bh = blockIdx.x, chunk = blockIdx.y;
    const int b = bh >> 3, h = bh & 7;

    __shared__ unsigned short ktT[64 * 72];   // [d][n], pad 72
    __shared__ unsigned short vtT[64 * 72];   // [e][n]
    __shared__ float ksl[16][64];

    const int t = threadIdx.x;
    const int w = t >> 6, lane = t & 63;
    const int ln = lane & 15, g = lane >> 4;

    // staging role: t<128 -> K, else V; slot = d-octet, ng = n-quad
    const bool isK = (t < 128);
    const int ts = isK ? t : t - 128;
    const int slot = ts & 7;
    const int ng = ts >> 3;                   // 0..15

    const size_t base = ((size_t)b * Nc + (size_t)chunk * 512) * QKVC + h * 64
                      + (isK ? Dc : 2 * Dc) + (size_t)slot * 8;

    unsigned short* Tdst = isK ? ktT : vtT;

    float4v acc[4];
#pragma unroll
    for (int j = 0; j < 4; ++j) acc[j] = {0.f, 0.f, 0.f, 0.f};
    float ks8[8] = {};

    for (int it = 0; it < 8; ++it) {
        // ---- stage: 4 n-rows x 8 d, reg-transposed to [d][n] b64 writes ----
        {
            const unsigned short* src = qkv + base + (size_t)(it * 64 + 4 * ng) * QKVC;
            ushort8v r0 = *reinterpret_cast<const ushort8v*>(src);
            ushort8v r1 = *reinterpret_cast<const ushort8v*>(src + QKVC);
            ushort8v r2 = *reinterpret_cast<const ushort8v*>(src + 2 * QKVC);
            ushort8v r3 = *reinterpret_cast<const ushort8v*>(src + 3 * QKVC);
#pragma unroll
            for (int i = 0; i < 8; ++i) {
                const int d = 8 * slot + i;
                unsigned long long pk = (unsigned long long)r0[i]
                    | ((unsigned long long)r1[i] << 16)
                    | ((unsigned long long)r2[i] << 32)
                    | ((unsigned long long)r3[i] << 48);
                *reinterpret_cast<unsigned long long*>(&Tdst[d * 72 + 4 * ng]) = pk;
                if (isK) ks8[i] += bf2f(r0[i]) + bf2f(r1[i]) + bf2f(r2[i]) + bf2f(r3[i]);
            }
        }
        __syncthreads();

        // ---- MFMA: wave w covers d in [w*16, w*16+16), all 64 e ----
        short8v afr[2], bfr[4][2];
#pragma unroll
        for (int kk = 0; kk < 2; ++kk)
            afr[kk] = *reinterpret_cast<const short8v*>(
                &ktT[(w * 16 + ln) * 72 + kk * 32 + g * 8]);
#pragma unroll
        for (int j = 0; j < 4; ++j)
#pragma unroll
            for (int kk = 0; kk < 2; ++kk)
                bfr[j][kk] = *reinterpret_cast<const short8v*>(
                    &vtT[(j * 16 + ln) * 72 + kk * 32 + g * 8]);
#pragma unroll
        for (int kk = 0; kk < 2; ++kk)
#pragma unroll
            for (int j = 0; j < 4; ++j)
                acc[j] = __builtin_amdgcn_mfma_f32_16x16x32_bf16(
                    afr[kk], bfr[j][kk], acc[j], 0, 0, 0);
        __syncthreads();
    }

    // ---- kv partials: D[row=g*4+r within 16, col=ln] -> d=w*16+g*4+r, e=j*16+ln
    float* kvpp = kvp + ((size_t)bh * 8 + chunk) * 4096;
#pragma unroll
    for (int j = 0; j < 4; ++j)
#pragma unroll
        for (int r = 0; r < 4; ++r)
            kvpp[(w * 16 + g * 4 + r) * 64 + j * 16 + ln] = acc[j][r];

    // ---- ksum (v2-proven path) ----
    if (isK) {
#pragma unroll
        for (int i = 0; i < 8; ++i) ksl[ng][8 * slot + i] = ks8[i];
    }
    __syncthreads();
    if (t < 64) {
        float s = 0.f;
#pragma unroll
        for (int c = 0; c < 16; ++c) s += ksl[c][t];
        ksp[((size_t)bh * 8 + chunk) * 64 + t] = s;
    }
}

// ---------------------------------------------------------------------------
// reduce 8 chunk-partials -> kvb (bf16, [d][e]) + ksum (f32)
// ---------------------------------------------------------------------------
__global__ __launch_bounds__(256) void kv_reduce(
    const float* __restrict__ kvp, const float* __restrict__ ksp,
    unsigned short* __restrict__ kvb, float* __restrict__ ksum)
{
    const int bh = blockIdx.x, t = threadIdx.x;
    const float* src = kvp + (size_t)bh * 8 * 4096;
#pragma unroll
    for (int i = 0; i < 16; ++i) {
        const int idx = i * 256 + t;
        float s = 0.f;
#pragma unroll
        for (int c = 0; c < 8; ++c) s += src[c * 4096 + idx];
        kvb[(size_t)bh * 4096 + idx] = f2bf(s);
    }
    if (t < 64) {
        float s = 0.f;
#pragma unroll
        for (int c = 0; c < 8; ++c) s += ksp[((size_t)bh * 8 + c) * 64 + t];
        ksum[bh * 64 + t] = s;
    }
}

// ---------------------------------------------------------------------------
// MT[b][c][h*64+d] = sum_e kv[b,h,d,e] * wp[c, h*64+e]   (bf16 out)
// ---------------------------------------------------------------------------
__global__ __launch_bounds__(256) void gemm_M(
    const unsigned short* __restrict__ kvb,   // [64][4096]
    const unsigned short* __restrict__ wp,    // [512][512]
    unsigned short* __restrict__ MT)          // [8][512][512]
{
    const int bh = blockIdx.x, b = bh >> 3, h = bh & 7;
    const int t = threadIdx.x, w = t >> 6, lane = t & 63;
    const int ln = lane & 15, g = lane >> 4;

    float4v acc[8][4];
#pragma unroll
    for (int i = 0; i < 8; ++i)
#pragma unroll
        for (int j = 0; j < 4; ++j) acc[i][j] = {0.f, 0.f, 0.f, 0.f};

#pragma unroll
    for (int kk = 0; kk < 2; ++kk) {
        short8v a[8], bf[4];
#pragma unroll
        for (int i = 0; i < 8; ++i)
            a[i] = *reinterpret_cast<const short8v*>(
                wp + (size_t)(w * 128 + i * 16 + ln) * 512 + h * 64 + kk * 32 + g * 8);
#pragma unroll
        for (int j = 0; j < 4; ++j)
            bf[j] = *reinterpret_cast<const short8v*>(
                kvb + (size_t)bh * 4096 + (j * 16 + ln) * 64 + kk * 32 + g * 8);
#pragma unroll
        for (int i = 0; i < 8; ++i)
#pragma unroll
            for (int j = 0; j < 4; ++j)
                acc[i][j] = __builtin_amdgcn_mfma_f32_16x16x32_bf16(a[i], bf[j], acc[i][j], 0, 0, 0);
    }

#pragma unroll
    for (int i = 0; i < 8; ++i) {
        const int c0 = w * 128 + i * 16 + g * 4;
#pragma unroll
        for (int j = 0; j < 4; ++j) {
            const int d = j * 16 + ln;
#pragma unroll
            for (int r = 0; r < 4; ++r)
                MT[(size_t)b * 262144 + (size_t)(c0 + r) * 512 + h * 64 + d] =
                    f2bf(acc[i][j][r]);
        }
    }
}

// ---------------------------------------------------------------------------
// q' = q / (q . ksum_h + eps), in place (bf16)
// ---------------------------------------------------------------------------
__global__ __launch_bounds__(256) void q_scale(
    unsigned short* __restrict__ qkv, const float* __restrict__ ksum)
{
    __shared__ float kss[512];
    const int blk = blockIdx.x;          // 1024
    const int b = blk >> 7;
    const int t = threadIdx.x;
    kss[t] = ksum[b * 512 + t];
    kss[t + 256] = ksum[b * 512 + 256 + t];
    __syncthreads();

    const int row = blk * 32 + (t >> 3);
    const int h = t & 7;
    unsigned short* p = qkv + (size_t)row * QKVC + h * 64;

    ushort8v v[8];
#pragma unroll
    for (int s = 0; s < 8; ++s) v[s] = *reinterpret_cast<const ushort8v*>(p + s * 8);

    float den = EPSF;
#pragma unroll
    for (int s = 0; s < 8; ++s)
#pragma unroll
        for (int m = 0; m < 8; ++m)
            den += bf2f(v[s][m]) * kss[h * 64 + s * 8 + m];
    const float inv = 1.0f / den;

#pragma unroll
    for (int s = 0; s < 8; ++s) {
        ushort8v o;
#pragma unroll
        for (int m = 0; m < 8; ++m) o[m] = f2bf(bf2f(v[s][m]) * inv);
        *reinterpret_cast<ushort8v*>(p + s * 8) = o;
    }
}

// ---------------------------------------------------------------------------
// out = q' @ MT_b^T + bias  (f32 out), ring-3
// ---------------------------------------------------------------------------
__global__ __launch_bounds__(512, 2) void gemm_out(
    const unsigned short* __restrict__ A,    // qkvb, lda 1536
    const unsigned short* __restrict__ Bt,   // MT [8][512][512]
    const float* __restrict__ bias,
    float* __restrict__ out)                 // [32768,512]
{
    constexpr int LDA = 1536, LDB = 512, NT = 8;
    __shared__ unsigned short ring[3][24576];

    const int t = threadIdx.x;
    const int orig = blockIdx.x;
    const int wg = (orig & 7) * 64 + (orig >> 3);   // nwg=512, %8==0
    const int bm = (wg >> 2) * 256;
    const int bn = (wg & 3) * 128;
    const unsigned short* Bm = Bt + (size_t)(bm >> 12) * 262144;

    const int w = t >> 6, lane = t & 63;
    const int ln = lane & 15, g = lane >> 4;
    const int wr = (w >> 1) * 64;
    const int wc = (w & 1) * 64;
    const int l7 = ln & 7;

    const int rs = t >> 3;
    const int ci = t & 7;
    const int swz = ci ^ (rs & 7);
    const unsigned short* As0 = A + (size_t)(bm + rs) * LDA + swz * 8;
    const unsigned short* As1 = A + (size_t)(bm + 64 + rs) * LDA + swz * 8;
    const unsigned short* As2 = A + (size_t)(bm + 128 + rs) * LDA + swz * 8;
    const unsigned short* As3 = A + (size_t)(bm + 192 + rs) * LDA + swz * 8;
    const unsigned short* Bs0 = Bm + (size_t)(bn + rs) * LDB + swz * 8;
    const unsigned short* Bs1 = Bm + (size_t)(bn + 64 + rs) * LDB + swz * 8;

#define STAGEO(Tt) do {                                                        \
        const int k0_ = (Tt) * 64;                                             \
        unsigned short* dA_ = &ring[(Tt) % 3][0];                              \
        unsigned short* dB_ = &ring[(Tt) % 3][16384];                          \
        llds16(As0 + k0_, dA_ + (size_t)t * 8);                                \
        llds16(As1 + k0_, dA_ + (size_t)(512 + t) * 8);                        \
        llds16(As2 + k0_, dA_ + (size_t)(1024 + t) * 8);                       \
        llds16(As3 + k0_, dA_ + (size_t)(1536 + t) * 8);                       \
        llds16(Bs0 + k0_, dB_ + (size_t)t * 8);                                \
        llds16(Bs1 + k0_, dB_ + (size_t)(512 + t) * 8);                        \
    } while (0)

    float4v acc[4][4];
#pragma unroll
    for (int i = 0; i < 4; ++i)
#pragma unroll
        for (int j = 0; j < 4; ++j) acc[i][j] = {0.f, 0.f, 0.f, 0.f};

    STAGEO(0);
    STAGEO(1);
    asm volatile("s_waitcnt vmcnt(6)" ::: "memory");
    __builtin_amdgcn_s_barrier();
    __builtin_amdgcn_sched_barrier(0);

#pragma unroll
    for (int T = 0; T < NT; ++T) {
        if (T + 2 < NT) STAGEO(T + 2);

        const unsigned short* base = &ring[T % 3][0];
        short8v a[4][2], b[4][2];
#pragma unroll
        for (int i = 0; i < 4; ++i)
#pragma unroll
            for (int kk = 0; kk < 2; ++kk) {
                const int row = wr + i * 16 + ln;
                a[i][kk] = *reinterpret_cast<const short8v*>(
                    base + row * 64 + (((kk * 4 + g) ^ l7) << 3));
            }
#pragma unroll
        for (int j = 0; j < 4; ++j)
#pragma unroll
            for (int kk = 0; kk < 2; ++kk) {
                const int row = wc + j * 16 + ln;
                b[j][kk] = *reinterpret_cast<const short8v*>(
                    base + 16384 + row * 64 + (((kk * 4 + g) ^ l7) << 3));
            }

        __builtin_amdgcn_s_setprio(1);
#pragma unroll
        for (int kk = 0; kk < 2; ++kk)
#pragma unroll
            for (int i = 0; i < 4; ++i)
#pragma unroll
                for (int j = 0; j < 4; ++j)
                    acc[i][j] = __builtin_amdgcn_mfma_f32_16x16x32_bf16(
                        a[i][kk], b[j][kk], acc[i][j], 0, 0, 0);
        __builtin_amdgcn_s_setprio(0);

        if (T + 1 < NT) {
            if (T + 2 < NT)
                asm volatile("s_waitcnt vmcnt(6)" ::: "memory");
            else
                asm volatile("s_waitcnt vmcnt(0)" ::: "memory");
            __builtin_amdgcn_s_barrier();
            __builtin_amdgcn_sched_barrier(0);
        }
    }
#undef STAGEO

#pragma unroll
    for (int i = 0; i < 4; ++i) {
        const int Rb = bm + wr + i * 16 + g * 4;
#pragma unroll
        for (int j = 0; j < 4; ++j) {
            const int Cc = bn + wc + j * 16 + ln;
            const float bv = bias[Cc];
#pragma unroll
            for (int r = 0; r < 4; ++r)
                out[(size_t)(Rb + r) * 512 + Cc] = acc[i][j][r] + bv;
        }
    }
}

// ---------------------------------------------------------------------------
extern "C" void kernel_launch(void* const* d_in, const int* in_sizes, int n_in,
                              void* d_out, int out_size, void* d_ws, size_t ws_size,
                              hipStream_t stream)
{
    const float* x      = (const float*)d_in[0];  // [8,4096,512]
    const float* w_qkv  = (const float*)d_in[1];  // [1536,512]
    const float* w_proj = (const float*)d_in[2];  // [512,512]
    const float* b_proj = (const float*)d_in[3];  // [512]
    float* out = (float*)d_out;

    char* ws = (char*)d_ws;
    unsigned short* qkvb = (unsigned short*)ws;                    // 96 MiB
    size_t off = (size_t)32768 * 1536 * 2;
    unsigned short* xb   = (unsigned short*)(ws + off); off += (size_t)32768 * 512 * 2;
    unsigned short* wqb  = (unsigned short*)(ws + off); off += (size_t)1536 * 512 * 2;
    unsigned short* wpb  = (unsigned short*)(ws + off); off += (size_t)512 * 512 * 2;
    float* kvp           = (float*)(ws + off);          off += (size_t)64 * 8 * 4096 * 4;
    float* ksp           = (float*)(ws + off);          off += (size_t)64 * 8 * 64 * 4;
    unsigned short* kvb  = (unsigned short*)(ws + off); off += (size_t)64 * 4096 * 2;
    float* ksumb         = (float*)(ws + off);          off += (size_t)64 * 64 * 4;
    unsigned short* MT   = (unsigned short*)(ws + off); off += (size_t)8 * 512 * 512 * 2;

    // 1) convert inputs to bf16
    cvt_f32_bf16<<<dim3((32768 * 512 / 8 + 255) / 256), dim3(256), 0, stream>>>(x, xb, 32768 * 512 / 8);
    cvt_weights<<<dim3(((1536 * 512 + 512 * 512) / 8 + 255) / 256), dim3(256), 0, stream>>>(
        w_qkv, w_proj, wqb, wpb);

    // 2) qkv = elu1(x @ w_qkv^T) (elu on cols<1024), bf16 out — ring-3
    gemm_qkv<<<dim3(1536), dim3(512), 0, stream>>>(xb, wqb, qkvb);

    // 3) kv partials (v4: MFMA on transposed bf16 tiles) + reduce
    kv_part<<<dim3(64, 8), dim3(256), 0, stream>>>(qkvb, kvp, ksp);
    kv_reduce<<<dim3(64), dim3(256), 0, stream>>>(kvp, ksp, kvb, ksumb);

    // 4) MT_b = (kv_h @ wp_h^T) stacked, per batch
    gemm_M<<<dim3(64), dim3(256), 0, stream>>>(kvb, wpb, MT);

    // 5) q' = q / (q.ksum + eps), in place
    q_scale<<<dim3(1024), dim3(256), 0, stream>>>(qkvb, ksumb);

    // 6) out = q' @ MT_b^T + bias (f32) — ring-3
    gemm_out<<<dim3(512), dim3(512), 0, stream>>>(qkvb, MT, b_proj, out);
}